// Round 1
// baseline (1350.789 us; speedup 1.0000x reference)
//
#include <hip/hip_runtime.h>
#include <hip/hip_bf16.h>

#define ALPHA 0.05f
#define SLOPE 0.2f

// ---------------- CSR build ----------------

__global__ void hist_kernel(const int* __restrict__ dst, int* __restrict__ counts, int E) {
    int e = blockIdx.x * blockDim.x + threadIdx.x;
    if (e < E) atomicAdd(&counts[dst[e]], 1);
}

__global__ __launch_bounds__(1024) void scan_kernel(const int* __restrict__ counts,
                                                    int* __restrict__ offsets, int n) {
    __shared__ int sdata[1024];
    __shared__ int srun;
    if (threadIdx.x == 0) srun = 0;
    __syncthreads();
    for (int base = 0; base < n; base += 1024) {
        int i = base + (int)threadIdx.x;
        int v = (i < n) ? counts[i] : 0;
        sdata[threadIdx.x] = v;
        __syncthreads();
        for (int off = 1; off < 1024; off <<= 1) {
            int t = (threadIdx.x >= off) ? sdata[threadIdx.x - off] : 0;
            __syncthreads();
            sdata[threadIdx.x] += t;
            __syncthreads();
        }
        int incl = sdata[threadIdx.x];
        int run = srun;
        if (i < n) offsets[i + 1] = run + incl;
        __syncthreads();
        if (threadIdx.x == 1023) srun = run + incl;
        __syncthreads();
    }
    if (threadIdx.x == 0) offsets[0] = 0;
}

__global__ void scatter_kernel(const int* __restrict__ src, const int* __restrict__ dst,
                               const int* __restrict__ et, int* __restrict__ cursor,
                               int* __restrict__ src_s, int* __restrict__ dst_s,
                               int* __restrict__ et_s, int E) {
    int e = blockIdx.x * blockDim.x + threadIdx.x;
    if (e >= E) return;
    int d = dst[e];
    int pos = atomicAdd(&cursor[d], 1);
    src_s[pos] = src[e];
    dst_s[pos] = d;
    et_s[pos]  = et[e];
}

// ---------------- matmuls (f32) ----------------

// C[M,N] = A[M,K] @ W[K,N] (+bias) (+=C). N multiple of 64, K multiple of 16.
template<bool BIAS, bool ACC>
__global__ __launch_bounds__(256) void matmul64(const float* __restrict__ A,
                                                const float* __restrict__ W,
                                                const float* __restrict__ bias,
                                                float* __restrict__ C,
                                                int M, int K, int N) {
    __shared__ float As[16][68];
    __shared__ float Bs[16][68];
    int bm = blockIdx.y * 64, bn = blockIdx.x * 64;
    int tx = threadIdx.x % 16, ty = threadIdx.x / 16;
    float acc[4][4] = {};
    for (int k0 = 0; k0 < K; k0 += 16) {
        for (int i = threadIdx.x; i < 64 * 16; i += 256) {
            int mm = i / 16, kk = i % 16;
            int gm = bm + mm;
            As[kk][mm] = (gm < M) ? A[(long)gm * K + k0 + kk] : 0.f;
        }
        for (int i = threadIdx.x; i < 16 * 64; i += 256) {
            int kk = i / 64, nn = i % 64;
            Bs[kk][nn] = W[(long)(k0 + kk) * N + bn + nn];
        }
        __syncthreads();
#pragma unroll
        for (int kk = 0; kk < 16; ++kk) {
            float a[4], b[4];
#pragma unroll
            for (int i = 0; i < 4; ++i) a[i] = As[kk][ty * 4 + i];
#pragma unroll
            for (int j = 0; j < 4; ++j) b[j] = Bs[kk][tx * 4 + j];
#pragma unroll
            for (int i = 0; i < 4; ++i)
#pragma unroll
                for (int j = 0; j < 4; ++j) acc[i][j] += a[i] * b[j];
        }
        __syncthreads();
    }
#pragma unroll
    for (int i = 0; i < 4; ++i) {
        int gm = bm + ty * 4 + i;
        if (gm >= M) continue;
#pragma unroll
        for (int j = 0; j < 4; ++j) {
            int gn = bn + tx * 4 + j;
            float v = acc[i][j];
            if (BIAS) v += bias[gn];
            if (ACC) v += C[(long)gm * N + gn];
            C[(long)gm * N + gn] = v;
        }
    }
}

// C[M,16] = A[M,K] @ W[K,16] (+=). K <= 256.
template<bool ACC>
__global__ __launch_bounds__(256) void matmul_n16(const float* __restrict__ A,
                                                  const float* __restrict__ W,
                                                  float* __restrict__ C, int M, int K) {
    __shared__ float Ws[256 * 16];
    for (int i = threadIdx.x; i < K * 16; i += 256) Ws[i] = W[i];
    __syncthreads();
    int m = blockIdx.x * 16 + threadIdx.x / 16;
    int nn = threadIdx.x % 16;
    if (m >= M) return;
    const float4* a4 = reinterpret_cast<const float4*>(A + (long)m * K);
    float s = 0.f;
    for (int k4 = 0; k4 < K / 4; ++k4) {
        float4 av = a4[k4];
        int k = k4 * 4;
        s += av.x * Ws[(k + 0) * 16 + nn];
        s += av.y * Ws[(k + 1) * 16 + nn];
        s += av.z * Ws[(k + 2) * 16 + nn];
        s += av.w * Ws[(k + 3) * 16 + nn];
    }
    if (ACC) s += C[(long)m * 16 + nn];
    C[(long)m * 16 + nn] = s;
}

// ---------------- attention pieces ----------------

// el[n,h] = dot(feat[n,h,:], al[h,:]); er likewise
template<int H, int OUT>
__global__ void attn_lr(const float* __restrict__ feat, const float* __restrict__ al,
                        const float* __restrict__ ar, float* __restrict__ el,
                        float* __restrict__ er, int N) {
    int gid = blockIdx.x * blockDim.x + threadIdx.x;
    int n = gid / H, h = gid % H;
    if (n >= N) return;
    const float* fr = feat + (long)n * H * OUT + h * OUT;
    float sl = 0.f, sr = 0.f;
#pragma unroll
    for (int o = 0; o < OUT; ++o) {
        float f = fr[o];
        sl += f * al[h * OUT + o];
        sr += f * ar[h * OUT + o];
    }
    el[n * H + h] = sl;
    er[n * H + h] = sr;
}

// et_att[t,h] = sum_d (eemb[t] @ We)[h*64+d] * ae[h,d]; edim=64, K=64, T=6
template<int H>
__global__ void etype_att(const float* __restrict__ eemb, const float* __restrict__ We,
                          const float* __restrict__ ae, float* __restrict__ out) {
    int idx = threadIdx.x;
    if (idx >= 6 * H) return;
    int t = idx / H, h = idx % H;
    float s = 0.f;
    for (int d = 0; d < 64; ++d) {
        float w = 0.f;
        for (int k = 0; k < 64; ++k) w += eemb[t * 64 + k] * We[k * (H * 64) + h * 64 + d];
        s += w * ae[h * 64 + d];
    }
    out[t * H + h] = s;
}

// e_csr[pos,h] = leaky_relu(el[src]+er[dst]+et_att[etype])
template<int H>
__global__ void edge_logits(const float* __restrict__ el, const float* __restrict__ er,
                            const float* __restrict__ etatt,
                            const int* __restrict__ src_s, const int* __restrict__ dst_s,
                            const int* __restrict__ et_s, float* __restrict__ e_csr, int E) {
    int p = blockIdx.x * blockDim.x + threadIdx.x;
    if (p >= E) return;
    int s = src_s[p], d = dst_s[p], t = et_s[p];
#pragma unroll
    for (int h = 0; h < H; ++h) {
        float v = el[s * H + h] + er[d * H + h] + etatt[t * H + h];
        v = v > 0.f ? v : SLOPE * v;
        e_csr[(long)p * H + h] = v;
    }
}

// per (dst, head): softmax over incoming edges, optional residual blend, write a in place
template<int H, bool BLEND, bool SAVE>
__global__ void edge_softmax(const int* __restrict__ offsets, float* __restrict__ e_csr,
                             const float* __restrict__ a0, float* __restrict__ a0_out, int N) {
    int gid = blockIdx.x * blockDim.x + threadIdx.x;
    int d = gid / H, h = gid % H;
    if (d >= N) return;
    int lo = offsets[d], hi = offsets[d + 1];
    float m = -INFINITY;
    for (int p = lo; p < hi; ++p) m = fmaxf(m, e_csr[(long)p * H + h]);
    float ssum = 0.f;
    for (int p = lo; p < hi; ++p) ssum += expf(e_csr[(long)p * H + h] - m);
    float inv = (ssum > 0.f) ? 1.0f / ssum : 0.f;
    for (int p = lo; p < hi; ++p) {
        float a = expf(e_csr[(long)p * H + h] - m) * inv;
        if (BLEND) a = a * (1.0f - ALPHA) + a0[(long)p * H + h] * ALPHA;
        e_csr[(long)p * H + h] = a;
        if (SAVE) a0_out[(long)p * H + h] = a;
    }
}

// rst[d, :] = sum_{edges p into d} a[p, head(c)] * feat[src_p, c]
template<int H, int OUT>
__global__ __launch_bounds__(256) void aggregate(const int* __restrict__ offsets,
                                                 const int* __restrict__ src_s,
                                                 const float* __restrict__ a_csr,
                                                 const float* __restrict__ feat,
                                                 float* __restrict__ rst, int N) {
    constexpr int CH = H * OUT;
    constexpr int TPD = CH / 4;
    int tid = blockIdx.x * blockDim.x + threadIdx.x;
    int d = tid / TPD;
    int t = tid % TPD;
    if (d >= N) return;
    int lo = offsets[d], hi = offsets[d + 1];
    int c = t * 4;
    int h = c / OUT;
    float4 acc = {0.f, 0.f, 0.f, 0.f};
    for (int p = lo; p < hi; ++p) {
        int s = src_s[p];
        float a = a_csr[(long)p * H + h];
        float4 f = *reinterpret_cast<const float4*>(&feat[(long)s * CH + c]);
        acc.x += f.x * a;
        acc.y += f.y * a;
        acc.z += f.z * a;
        acc.w += f.w * a;
    }
    *reinterpret_cast<float4*>(&rst[(long)d * CH + c]) = acc;
}

__global__ void elu_kernel(float* __restrict__ buf, long n4) {
    long i = (long)blockIdx.x * blockDim.x + threadIdx.x;
    if (i >= n4) return;
    float4 v = reinterpret_cast<float4*>(buf)[i];
    v.x = v.x > 0.f ? v.x : expf(v.x) - 1.f;
    v.y = v.y > 0.f ? v.y : expf(v.y) - 1.f;
    v.z = v.z > 0.f ? v.z : expf(v.z) - 1.f;
    v.w = v.w > 0.f ? v.w : expf(v.w) - 1.f;
    reinterpret_cast<float4*>(buf)[i] = v;
}

// ---------------- launch ----------------

extern "C" void kernel_launch(void* const* d_in, const int* in_sizes, int n_in,
                              void* d_out, int out_size, void* d_ws, size_t ws_size,
                              hipStream_t stream) {
    const float* x0   = (const float*)d_in[0];
    const float* x1   = (const float*)d_in[1];
    const float* x2   = (const float*)d_in[2];
    const float* fcw0 = (const float*)d_in[3];
    const float* fcb0 = (const float*)d_in[4];
    const float* fcw1 = (const float*)d_in[5];
    const float* fcb1 = (const float*)d_in[6];
    const float* fcw2 = (const float*)d_in[7];
    const float* fcb2 = (const float*)d_in[8];
    const float* W0   = (const float*)d_in[9];
    const float* We0  = (const float*)d_in[10];
    const float* eemb0= (const float*)d_in[11];
    const float* al0  = (const float*)d_in[12];
    const float* ar0  = (const float*)d_in[13];
    const float* ae0  = (const float*)d_in[14];
    const float* W1   = (const float*)d_in[15];
    const float* We1  = (const float*)d_in[16];
    const float* eemb1= (const float*)d_in[17];
    const float* al1  = (const float*)d_in[18];
    const float* ar1  = (const float*)d_in[19];
    const float* ae1  = (const float*)d_in[20];
    const float* resW1= (const float*)d_in[21];
    const float* W2   = (const float*)d_in[22];
    const float* We2  = (const float*)d_in[23];
    const float* eemb2= (const float*)d_in[24];
    const float* al2  = (const float*)d_in[25];
    const float* ar2  = (const float*)d_in[26];
    const float* ae2  = (const float*)d_in[27];
    const float* resW2= (const float*)d_in[28];
    const int* src    = (const int*)d_in[29];
    const int* dst    = (const int*)d_in[30];
    const int* etype  = (const int*)d_in[31];

    const int n0 = in_sizes[0] / 128;
    const int n1 = in_sizes[1] / 256;
    const int n2 = in_sizes[2] / 64;
    const int N  = n0 + n1 + n2;
    const int E  = in_sizes[29];

    char* w = (char*)d_ws;
    auto alloc = [&](size_t bytes) {
        char* p = w;
        w += (bytes + 255) & ~(size_t)255;
        return p;
    };
    int*   counts  = (int*)alloc((size_t)N * 4);
    int*   offsets = (int*)alloc((size_t)(N + 1) * 4);
    int*   cursor  = (int*)alloc((size_t)N * 4);
    int*   src_s   = (int*)alloc((size_t)E * 4);
    int*   dst_s   = (int*)alloc((size_t)E * 4);
    int*   et_s    = (int*)alloc((size_t)E * 4);
    float* e_csr   = (float*)alloc((size_t)E * 8 * 4);
    float* a0_csr  = (float*)alloc((size_t)E * 8 * 4);
    float* h0      = (float*)alloc((size_t)N * 64 * 4);
    float* feat    = (float*)alloc((size_t)N * 256 * 4);
    float* h1      = (float*)alloc((size_t)N * 256 * 4);
    float* h2      = (float*)alloc((size_t)N * 256 * 4);
    float* el      = (float*)alloc((size_t)N * 8 * 4);
    float* er      = (float*)alloc((size_t)N * 8 * 4);
    float* etatt   = (float*)alloc(6 * 8 * 4);
    float* feat2   = h0;  // h0 dead after layer-0 feat matmul
    float* out     = (float*)d_out;

    const int TB = 256;
    int eb = (E + TB - 1) / TB;

    // ---- CSR build ----
    hipMemsetAsync(counts, 0, (size_t)N * 4, stream);
    hist_kernel<<<eb, TB, 0, stream>>>(dst, counts, E);
    scan_kernel<<<1, 1024, 0, stream>>>(counts, offsets, N);
    hipMemcpyAsync(cursor, offsets, (size_t)N * 4, hipMemcpyDeviceToDevice, stream);
    scatter_kernel<<<eb, TB, 0, stream>>>(src, dst, etype, cursor, src_s, dst_s, et_s, E);

    // ---- input FC: h0 = concat(x_i @ fcw_i + fcb_i) ----
    {
        dim3 g0(1, (n0 + 63) / 64);
        matmul64<true, false><<<g0, TB, 0, stream>>>(x0, fcw0, fcb0, h0, n0, 128, 64);
        dim3 g1(1, (n1 + 63) / 64);
        matmul64<true, false><<<g1, TB, 0, stream>>>(x1, fcw1, fcb1, h0 + (long)n0 * 64, n1, 256, 64);
        dim3 g2(1, (n2 + 63) / 64);
        matmul64<true, false><<<g2, TB, 0, stream>>>(x2, fcw2, fcb2, h0 + (long)(n0 + n1) * 64, n2, 64, 64);
    }

    int nb_nh8 = (N * 8 + TB - 1) / TB;
    int nb_agg = (N * 64 + TB - 1) / TB;
    long n4 = (long)N * 256 / 4;
    int nb_elu = (int)((n4 + TB - 1) / TB);

    // ---- layer 0 ----
    {
        dim3 g(256 / 64, (N + 63) / 64);
        matmul64<false, false><<<g, TB, 0, stream>>>(h0, W0, nullptr, feat, N, 64, 256);
        attn_lr<8, 32><<<nb_nh8, TB, 0, stream>>>(feat, al0, ar0, el, er, N);
        etype_att<8><<<1, 64, 0, stream>>>(eemb0, We0, ae0, etatt);
        edge_logits<8><<<eb, TB, 0, stream>>>(el, er, etatt, src_s, dst_s, et_s, e_csr, E);
        edge_softmax<8, false, true><<<nb_nh8, TB, 0, stream>>>(offsets, e_csr, nullptr, a0_csr, N);
        aggregate<8, 32><<<nb_agg, TB, 0, stream>>>(offsets, src_s, e_csr, feat, h1, N);
        elu_kernel<<<nb_elu, TB, 0, stream>>>(h1, n4);
    }

    // ---- layer 1 ----
    {
        dim3 g(256 / 64, (N + 63) / 64);
        matmul64<false, false><<<g, TB, 0, stream>>>(h1, W1, nullptr, feat, N, 256, 256);
        attn_lr<8, 32><<<nb_nh8, TB, 0, stream>>>(feat, al1, ar1, el, er, N);
        etype_att<8><<<1, 64, 0, stream>>>(eemb1, We1, ae1, etatt);
        edge_logits<8><<<eb, TB, 0, stream>>>(el, er, etatt, src_s, dst_s, et_s, e_csr, E);
        edge_softmax<8, true, false><<<nb_nh8, TB, 0, stream>>>(offsets, e_csr, a0_csr, nullptr, N);
        aggregate<8, 32><<<nb_agg, TB, 0, stream>>>(offsets, src_s, e_csr, feat, h2, N);
        matmul64<false, true><<<g, TB, 0, stream>>>(h1, resW1, nullptr, h2, N, 256, 256);
        elu_kernel<<<nb_elu, TB, 0, stream>>>(h2, n4);
    }

    // ---- layer 2 (H=1, OUT=16, no activation) ----
    {
        matmul_n16<false><<<(N + 15) / 16, TB, 0, stream>>>(h2, W2, feat2, N, 256);
        int nb_nh1 = (N + TB - 1) / TB;
        attn_lr<1, 16><<<nb_nh1, TB, 0, stream>>>(feat2, al2, ar2, el, er, N);
        etype_att<1><<<1, 64, 0, stream>>>(eemb2, We2, ae2, etatt);
        edge_logits<1><<<eb, TB, 0, stream>>>(el, er, etatt, src_s, dst_s, et_s, e_csr, E);
        edge_softmax<1, false, false><<<nb_nh1, TB, 0, stream>>>(offsets, e_csr, nullptr, nullptr, N);
        int nb_agg2 = (N * 4 + TB - 1) / TB;
        aggregate<1, 16><<<nb_agg2, TB, 0, stream>>>(offsets, src_s, e_csr, feat2, out, N);
        matmul_n16<true><<<(N + 15) / 16, TB, 0, stream>>>(h2, resW2, out, N, 256);
    }
}

// Round 2
// 1052.779 us; speedup vs baseline: 1.2831x; 1.2831x over previous
//
#include <hip/hip_runtime.h>
#include <hip/hip_bf16.h>

#define ALPHA 0.05f
#define SLOPE 0.2f

typedef __attribute__((ext_vector_type(8))) short short8v;
typedef __attribute__((ext_vector_type(4))) float floatx4;

__device__ inline ushort f2b(float f) {
    uint u = __float_as_uint(f);
    return (ushort)((u + 0x7fffu + ((u >> 16) & 1u)) >> 16);
}
__device__ inline float b2f(ushort b) { return __uint_as_float(((uint)b) << 16); }

// ---------------- CSR build ----------------

__global__ void hist_kernel(const int* __restrict__ dst, int* __restrict__ counts, int E) {
    int e = blockIdx.x * blockDim.x + threadIdx.x;
    if (e < E) atomicAdd(&counts[dst[e]], 1);
}

__global__ __launch_bounds__(1024) void scan_kernel(const int* __restrict__ counts,
                                                    int* __restrict__ offsets, int n) {
    __shared__ int sdata[1024];
    __shared__ int srun;
    if (threadIdx.x == 0) srun = 0;
    __syncthreads();
    for (int base = 0; base < n; base += 1024) {
        int i = base + (int)threadIdx.x;
        int v = (i < n) ? counts[i] : 0;
        sdata[threadIdx.x] = v;
        __syncthreads();
        for (int off = 1; off < 1024; off <<= 1) {
            int t = (threadIdx.x >= off) ? sdata[threadIdx.x - off] : 0;
            __syncthreads();
            sdata[threadIdx.x] += t;
            __syncthreads();
        }
        int incl = sdata[threadIdx.x];
        int run = srun;
        if (i < n) offsets[i + 1] = run + incl;
        __syncthreads();
        if (threadIdx.x == 1023) srun = run + incl;
        __syncthreads();
    }
    if (threadIdx.x == 0) offsets[0] = 0;
}

__global__ void scatter_kernel(const int* __restrict__ src, const int* __restrict__ dst,
                               const int* __restrict__ et, int* __restrict__ cursor,
                               int* __restrict__ src_s, int* __restrict__ dst_s,
                               int* __restrict__ et_s, int E) {
    int e = blockIdx.x * blockDim.x + threadIdx.x;
    if (e >= E) return;
    int d = dst[e];
    int pos = atomicAdd(&cursor[d], 1);
    src_s[pos] = src[e];
    dst_s[pos] = d;
    et_s[pos]  = et[e];
}

// ---------------- weight prep: W[K][N] f32 -> Wt[N][K] bf16 ----------------

__global__ void wprep(const float* __restrict__ W, ushort* __restrict__ Wt, int K, int N) {
    int i = blockIdx.x * blockDim.x + threadIdx.x;
    if (i >= K * N) return;
    int k = i / N, n = i % N;
    Wt[(long)n * K + k] = f2b(W[i]);
}

// ---------------- bf16 MFMA GEMM: C[M,N] = A[M,K] @ Bt[N,K]^T ----------------
// A, Bt bf16 row-major. N multiple of 128, K multiple of 32. Out f32 or bf16.

template<bool F32OUT>
__global__ __launch_bounds__(256) void gemm_bf16(const ushort* __restrict__ A,
                                                 const ushort* __restrict__ Bt,
                                                 float* __restrict__ Cf,
                                                 ushort* __restrict__ Cb,
                                                 int M, int N, int K) {
    __shared__ ushort As[128][40];
    __shared__ ushort Bs[128][40];
    int bm = blockIdx.y * 128, bn = blockIdx.x * 128;
    int tid = threadIdx.x;
    int wave = tid >> 6, lane = tid & 63;
    int wm = (wave >> 1) * 64, wn = (wave & 1) * 64;
    floatx4 acc[4][4] = {};
    for (int k0 = 0; k0 < K; k0 += 32) {
#pragma unroll
        for (int it = 0; it < 2; ++it) {
            int idx = (tid + it * 256) * 8;
            int r = idx >> 5, c = idx & 31;
            int gr = bm + r;
            uint4 va = {0u, 0u, 0u, 0u};
            if (gr < M) va = *reinterpret_cast<const uint4*>(&A[(long)gr * K + k0 + c]);
            *reinterpret_cast<uint4*>(&As[r][c]) = va;
            uint4 vb = *reinterpret_cast<const uint4*>(&Bt[(long)(bn + r) * K + k0 + c]);
            *reinterpret_cast<uint4*>(&Bs[r][c]) = vb;
        }
        __syncthreads();
        int lr = lane & 15, lk = (lane >> 4) * 8;
        short8v af[4], bfr[4];
#pragma unroll
        for (int i = 0; i < 4; ++i)
            af[i] = *reinterpret_cast<const short8v*>(&As[wm + i * 16 + lr][lk]);
#pragma unroll
        for (int j = 0; j < 4; ++j)
            bfr[j] = *reinterpret_cast<const short8v*>(&Bs[wn + j * 16 + lr][lk]);
#pragma unroll
        for (int i = 0; i < 4; ++i)
#pragma unroll
            for (int j = 0; j < 4; ++j)
                acc[i][j] = __builtin_amdgcn_mfma_f32_16x16x32_bf16(af[i], bfr[j], acc[i][j], 0, 0, 0);
        __syncthreads();
    }
    int col = lane & 15, rbase = (lane >> 4) * 4;
#pragma unroll
    for (int i = 0; i < 4; ++i) {
#pragma unroll
        for (int r = 0; r < 4; ++r) {
            int gm = bm + wm + i * 16 + rbase + r;
            if (gm >= M) continue;
#pragma unroll
            for (int j = 0; j < 4; ++j) {
                int gn = bn + wn + j * 16 + col;
                float v = acc[i][j][r];
                if (F32OUT) Cf[(long)gm * N + gn] = v;
                else Cb[(long)gm * N + gn] = f2b(v);
            }
        }
    }
}

// ---------------- input FC (f32 compute, bf16 out): C[M,64] = A@W + b ----------------

__global__ __launch_bounds__(256) void matmul64_fc(const float* __restrict__ A,
                                                   const float* __restrict__ W,
                                                   const float* __restrict__ bias,
                                                   ushort* __restrict__ C,
                                                   int M, int K, int N) {
    __shared__ float As[16][68];
    __shared__ float Bs[16][68];
    int bm = blockIdx.y * 64, bn = blockIdx.x * 64;
    int tx = threadIdx.x % 16, ty = threadIdx.x / 16;
    float acc[4][4] = {};
    for (int k0 = 0; k0 < K; k0 += 16) {
        for (int i = threadIdx.x; i < 64 * 16; i += 256) {
            int mm = i / 16, kk = i % 16;
            int gm = bm + mm;
            As[kk][mm] = (gm < M) ? A[(long)gm * K + k0 + kk] : 0.f;
        }
        for (int i = threadIdx.x; i < 16 * 64; i += 256) {
            int kk = i / 64, nn = i % 64;
            Bs[kk][nn] = W[(long)(k0 + kk) * N + bn + nn];
        }
        __syncthreads();
#pragma unroll
        for (int kk = 0; kk < 16; ++kk) {
            float a[4], b[4];
#pragma unroll
            for (int i = 0; i < 4; ++i) a[i] = As[kk][ty * 4 + i];
#pragma unroll
            for (int j = 0; j < 4; ++j) b[j] = Bs[kk][tx * 4 + j];
#pragma unroll
            for (int i = 0; i < 4; ++i)
#pragma unroll
                for (int j = 0; j < 4; ++j) acc[i][j] += a[i] * b[j];
        }
        __syncthreads();
    }
#pragma unroll
    for (int i = 0; i < 4; ++i) {
        int gm = bm + ty * 4 + i;
        if (gm >= M) continue;
#pragma unroll
        for (int j = 0; j < 4; ++j) {
            int gn = bn + tx * 4 + j;
            C[(long)gm * N + gn] = f2b(acc[i][j] + bias[gn]);
        }
    }
}

// ---------------- small N=16 matmul, bf16 A: C[M,16] = A[M,K] @ W[K,16] (+=) ----------------

template<bool ACC>
__global__ __launch_bounds__(256) void matmul_n16b(const ushort* __restrict__ A,
                                                   const float* __restrict__ W,
                                                   float* __restrict__ C, int M, int K) {
    __shared__ float Ws[256 * 16];
    for (int i = threadIdx.x; i < K * 16; i += 256) Ws[i] = W[i];
    __syncthreads();
    int m = blockIdx.x * 16 + threadIdx.x / 16;
    int nn = threadIdx.x % 16;
    if (m >= M) return;
    float s = 0.f;
    for (int k8 = 0; k8 < K / 8; ++k8) {
        uint4 v = *reinterpret_cast<const uint4*>(&A[(long)m * K + k8 * 8]);
        const uint* vp = reinterpret_cast<const uint*>(&v);
#pragma unroll
        for (int q = 0; q < 4; ++q) {
            uint w2 = vp[q];
            float f0 = __uint_as_float((w2 & 0xffffu) << 16);
            float f1 = __uint_as_float(w2 & 0xffff0000u);
            int k = k8 * 8 + q * 2;
            s += f0 * Ws[(k + 0) * 16 + nn] + f1 * Ws[(k + 1) * 16 + nn];
        }
    }
    if (ACC) s += C[(long)m * 16 + nn];
    C[(long)m * 16 + nn] = s;
}

// ---------------- attention pieces ----------------

template<int H, int OUT>
__global__ void attn_lr(const float* __restrict__ feat, const float* __restrict__ al,
                        const float* __restrict__ ar, float* __restrict__ el,
                        float* __restrict__ er, int N) {
    int gid = blockIdx.x * blockDim.x + threadIdx.x;
    int n = gid / H, h = gid % H;
    if (n >= N) return;
    const float* fr = feat + (long)n * H * OUT + h * OUT;
    float sl = 0.f, sr = 0.f;
#pragma unroll
    for (int o = 0; o < OUT; ++o) {
        float f = fr[o];
        sl += f * al[h * OUT + o];
        sr += f * ar[h * OUT + o];
    }
    el[n * H + h] = sl;
    er[n * H + h] = sr;
}

template<int H>
__global__ void etype_att(const float* __restrict__ eemb, const float* __restrict__ We,
                          const float* __restrict__ ae, float* __restrict__ out) {
    int idx = threadIdx.x;
    if (idx >= 6 * H) return;
    int t = idx / H, h = idx % H;
    float s = 0.f;
    for (int d = 0; d < 64; ++d) {
        float w = 0.f;
        for (int k = 0; k < 64; ++k) w += eemb[t * 64 + k] * We[k * (H * 64) + h * 64 + d];
        s += w * ae[h * 64 + d];
    }
    out[t * H + h] = s;
}

template<int H>
__global__ void edge_logits(const float* __restrict__ el, const float* __restrict__ er,
                            const float* __restrict__ etatt,
                            const int* __restrict__ src_s, const int* __restrict__ dst_s,
                            const int* __restrict__ et_s, float* __restrict__ e_csr, int E) {
    int p = blockIdx.x * blockDim.x + threadIdx.x;
    if (p >= E) return;
    int s = src_s[p], d = dst_s[p], t = et_s[p];
#pragma unroll
    for (int h = 0; h < H; ++h) {
        float v = el[s * H + h] + er[d * H + h] + etatt[t * H + h];
        v = v > 0.f ? v : SLOPE * v;
        e_csr[(long)p * H + h] = v;
    }
}

template<int H, bool BLEND, bool SAVE>
__global__ void edge_softmax(const int* __restrict__ offsets, float* __restrict__ e_csr,
                             const float* __restrict__ a0, float* __restrict__ a0_out, int N) {
    int gid = blockIdx.x * blockDim.x + threadIdx.x;
    int d = gid / H, h = gid % H;
    if (d >= N) return;
    int lo = offsets[d], hi = offsets[d + 1];
    float m = -INFINITY;
    for (int p = lo; p < hi; ++p) m = fmaxf(m, e_csr[(long)p * H + h]);
    float ssum = 0.f;
    for (int p = lo; p < hi; ++p) ssum += expf(e_csr[(long)p * H + h] - m);
    float inv = (ssum > 0.f) ? 1.0f / ssum : 0.f;
    for (int p = lo; p < hi; ++p) {
        float a = expf(e_csr[(long)p * H + h] - m) * inv;
        if (BLEND) a = a * (1.0f - ALPHA) + a0[(long)p * H + h] * ALPHA;
        e_csr[(long)p * H + h] = a;
        if (SAVE) a0_out[(long)p * H + h] = a;
    }
}

// rst[d,:] = (res?) + sum_p a[p,h] * feat[src_p,:]; optional ELU; f32 or bf16 out
template<int H, int OUT, bool RESIN, bool ELU, bool BF16OUT>
__global__ __launch_bounds__(256) void aggregate(const int* __restrict__ offsets,
                                                 const int* __restrict__ src_s,
                                                 const float* __restrict__ a_csr,
                                                 const float* __restrict__ feat,
                                                 const ushort* __restrict__ resin,
                                                 float* __restrict__ outf,
                                                 ushort* __restrict__ outb, int N) {
    constexpr int CH = H * OUT;
    constexpr int TPD = CH / 4;
    int tid = blockIdx.x * blockDim.x + threadIdx.x;
    int d = tid / TPD;
    int t = tid % TPD;
    if (d >= N) return;
    int lo = offsets[d], hi = offsets[d + 1];
    int c = t * 4;
    int h = c / OUT;
    float4 acc = {0.f, 0.f, 0.f, 0.f};
    if (RESIN) {
        ushort4 r = *reinterpret_cast<const ushort4*>(&resin[(long)d * CH + c]);
        acc.x = b2f(r.x); acc.y = b2f(r.y); acc.z = b2f(r.z); acc.w = b2f(r.w);
    }
    for (int p = lo; p < hi; ++p) {
        int s = src_s[p];
        float a = a_csr[(long)p * H + h];
        float4 f = *reinterpret_cast<const float4*>(&feat[(long)s * CH + c]);
        acc.x += f.x * a;
        acc.y += f.y * a;
        acc.z += f.z * a;
        acc.w += f.w * a;
    }
    if (ELU) {
        acc.x = acc.x > 0.f ? acc.x : expf(acc.x) - 1.f;
        acc.y = acc.y > 0.f ? acc.y : expf(acc.y) - 1.f;
        acc.z = acc.z > 0.f ? acc.z : expf(acc.z) - 1.f;
        acc.w = acc.w > 0.f ? acc.w : expf(acc.w) - 1.f;
    }
    if (BF16OUT) {
        ushort4 o = {f2b(acc.x), f2b(acc.y), f2b(acc.z), f2b(acc.w)};
        *reinterpret_cast<ushort4*>(&outb[(long)d * CH + c]) = o;
    } else {
        *reinterpret_cast<float4*>(&outf[(long)d * CH + c]) = acc;
    }
}

// ---------------- launch ----------------

extern "C" void kernel_launch(void* const* d_in, const int* in_sizes, int n_in,
                              void* d_out, int out_size, void* d_ws, size_t ws_size,
                              hipStream_t stream) {
    const float* x0   = (const float*)d_in[0];
    const float* x1   = (const float*)d_in[1];
    const float* x2   = (const float*)d_in[2];
    const float* fcw0 = (const float*)d_in[3];
    const float* fcb0 = (const float*)d_in[4];
    const float* fcw1 = (const float*)d_in[5];
    const float* fcb1 = (const float*)d_in[6];
    const float* fcw2 = (const float*)d_in[7];
    const float* fcb2 = (const float*)d_in[8];
    const float* W0   = (const float*)d_in[9];
    const float* We0  = (const float*)d_in[10];
    const float* eemb0= (const float*)d_in[11];
    const float* al0  = (const float*)d_in[12];
    const float* ar0  = (const float*)d_in[13];
    const float* ae0  = (const float*)d_in[14];
    const float* W1   = (const float*)d_in[15];
    const float* We1  = (const float*)d_in[16];
    const float* eemb1= (const float*)d_in[17];
    const float* al1  = (const float*)d_in[18];
    const float* ar1  = (const float*)d_in[19];
    const float* ae1  = (const float*)d_in[20];
    const float* resW1= (const float*)d_in[21];
    const float* W2   = (const float*)d_in[22];
    const float* We2  = (const float*)d_in[23];
    const float* eemb2= (const float*)d_in[24];
    const float* al2  = (const float*)d_in[25];
    const float* ar2  = (const float*)d_in[26];
    const float* ae2  = (const float*)d_in[27];
    const float* resW2= (const float*)d_in[28];
    const int* src    = (const int*)d_in[29];
    const int* dst    = (const int*)d_in[30];
    const int* etype  = (const int*)d_in[31];

    const int n0 = in_sizes[0] / 128;
    const int n1 = in_sizes[1] / 256;
    const int n2 = in_sizes[2] / 64;
    const int N  = n0 + n1 + n2;
    const int E  = in_sizes[29];

    char* w = (char*)d_ws;
    auto alloc = [&](size_t bytes) {
        char* p = w;
        w += (bytes + 255) & ~(size_t)255;
        return p;
    };
    int*    counts  = (int*)alloc((size_t)N * 4);
    int*    offsets = (int*)alloc((size_t)(N + 1) * 4);
    int*    cursor  = (int*)alloc((size_t)N * 4);
    int*    src_s   = (int*)alloc((size_t)E * 4);
    int*    dst_s   = (int*)alloc((size_t)E * 4);
    int*    et_s    = (int*)alloc((size_t)E * 4);
    float*  e_csr   = (float*)alloc((size_t)E * 8 * 4);
    ushort* a0_csr  = (ushort*)alloc((size_t)E * 8 * 4);  // f32 a0 (layer0) -> reused as bf16 h2res
    ushort* h0bf    = (ushort*)alloc((size_t)N * 64 * 2);
    float*  feat    = (float*)alloc((size_t)N * 256 * 4);
    ushort* h1bf    = (ushort*)alloc((size_t)N * 256 * 2);
    ushort* h2bf    = (ushort*)alloc((size_t)N * 256 * 2);
    float*  el      = (float*)alloc((size_t)N * 8 * 4);
    float*  er      = (float*)alloc((size_t)N * 8 * 4);
    float*  etatt   = (float*)alloc(6 * 8 * 4);
    ushort* Wt0     = (ushort*)alloc((size_t)256 * 64 * 2);
    ushort* Wt1     = (ushort*)alloc((size_t)256 * 256 * 2);
    ushort* WtR     = (ushort*)alloc((size_t)256 * 256 * 2);
    float*  feat2   = (float*)alloc((size_t)N * 16 * 4);
    float*  a0f     = (float*)a0_csr;   // f32 view for layer-0 attention save
    ushort* h2res   = a0_csr;           // bf16 view, reused AFTER layer-1 softmax consumed a0
    float*  out     = (float*)d_out;

    const int TB = 256;
    int eb = (E + TB - 1) / TB;

    // ---- CSR build ----
    hipMemsetAsync(counts, 0, (size_t)N * 4, stream);
    hist_kernel<<<eb, TB, 0, stream>>>(dst, counts, E);
    scan_kernel<<<1, 1024, 0, stream>>>(counts, offsets, N);
    hipMemcpyAsync(cursor, offsets, (size_t)N * 4, hipMemcpyDeviceToDevice, stream);
    scatter_kernel<<<eb, TB, 0, stream>>>(src, dst, etype, cursor, src_s, dst_s, et_s, E);

    // ---- weight prep ----
    wprep<<<(64 * 256 + TB - 1) / TB, TB, 0, stream>>>(W0, Wt0, 64, 256);
    wprep<<<(256 * 256 + TB - 1) / TB, TB, 0, stream>>>(W1, Wt1, 256, 256);
    wprep<<<(256 * 256 + TB - 1) / TB, TB, 0, stream>>>(resW1, WtR, 256, 256);

    // ---- input FC: h0bf = concat(x_i @ fcw_i + fcb_i) ----
    {
        dim3 g0(1, (n0 + 63) / 64);
        matmul64_fc<<<g0, TB, 0, stream>>>(x0, fcw0, fcb0, h0bf, n0, 128, 64);
        dim3 g1(1, (n1 + 63) / 64);
        matmul64_fc<<<g1, TB, 0, stream>>>(x1, fcw1, fcb1, h0bf + (long)n0 * 64, n1, 256, 64);
        dim3 g2(1, (n2 + 63) / 64);
        matmul64_fc<<<g2, TB, 0, stream>>>(x2, fcw2, fcb2, h0bf + (long)(n0 + n1) * 64, n2, 64, 64);
    }

    int nb_nh8 = (N * 8 + TB - 1) / TB;
    int nb_agg = (N * 64 + TB - 1) / TB;
    dim3 gg(256 / 128, (N + 127) / 128);

    // ---- layer 0 ----
    {
        gemm_bf16<true><<<gg, TB, 0, stream>>>(h0bf, Wt0, feat, nullptr, N, 256, 64);
        attn_lr<8, 32><<<nb_nh8, TB, 0, stream>>>(feat, al0, ar0, el, er, N);
        etype_att<8><<<1, 64, 0, stream>>>(eemb0, We0, ae0, etatt);
        edge_logits<8><<<eb, TB, 0, stream>>>(el, er, etatt, src_s, dst_s, et_s, e_csr, E);
        edge_softmax<8, false, true><<<nb_nh8, TB, 0, stream>>>(offsets, e_csr, nullptr, a0f, N);
        aggregate<8, 32, false, true, true><<<nb_agg, TB, 0, stream>>>(
            offsets, src_s, e_csr, feat, nullptr, nullptr, h1bf, N);
    }

    // ---- layer 1 ----
    {
        gemm_bf16<true><<<gg, TB, 0, stream>>>(h1bf, Wt1, feat, nullptr, N, 256, 256);
        attn_lr<8, 32><<<nb_nh8, TB, 0, stream>>>(feat, al1, ar1, el, er, N);
        etype_att<8><<<1, 64, 0, stream>>>(eemb1, We1, ae1, etatt);
        edge_logits<8><<<eb, TB, 0, stream>>>(el, er, etatt, src_s, dst_s, et_s, e_csr, E);
        edge_softmax<8, true, false><<<nb_nh8, TB, 0, stream>>>(offsets, e_csr, a0f, nullptr, N);
        // a0 consumed; reuse its buffer for the bf16 residual h1 @ resW1
        gemm_bf16<false><<<gg, TB, 0, stream>>>(h1bf, WtR, nullptr, h2res, N, 256, 256);
        aggregate<8, 32, true, true, true><<<nb_agg, TB, 0, stream>>>(
            offsets, src_s, e_csr, feat, h2res, nullptr, h2bf, N);
    }

    // ---- layer 2 (H=1, OUT=16, residual, no activation) ----
    {
        matmul_n16b<false><<<(N + 15) / 16, TB, 0, stream>>>(h2bf, W2, feat2, N, 256);
        int nb_nh1 = (N + TB - 1) / TB;
        attn_lr<1, 16><<<nb_nh1, TB, 0, stream>>>(feat2, al2, ar2, el, er, N);
        etype_att<1><<<1, 64, 0, stream>>>(eemb2, We2, ae2, etatt);
        edge_logits<1><<<eb, TB, 0, stream>>>(el, er, etatt, src_s, dst_s, et_s, e_csr, E);
        edge_softmax<1, false, false><<<nb_nh1, TB, 0, stream>>>(offsets, e_csr, nullptr, nullptr, N);
        int nb_agg2 = (N * 4 + TB - 1) / TB;
        aggregate<1, 16, false, false, false><<<nb_agg2, TB, 0, stream>>>(
            offsets, src_s, e_csr, feat2, nullptr, out, nullptr, N);
        matmul_n16b<true><<<(N + 15) / 16, TB, 0, stream>>>(h2bf, resW2, out, N, 256);
    }
}

// Round 3
// 778.973 us; speedup vs baseline: 1.7341x; 1.3515x over previous
//
#include <hip/hip_runtime.h>
#include <hip/hip_bf16.h>

#define ALPHA 0.05f
#define SLOPE 0.2f

typedef __attribute__((ext_vector_type(8))) short short8v;
typedef __attribute__((ext_vector_type(4))) float floatx4;

__device__ inline ushort f2b(float f) {
    uint u = __float_as_uint(f);
    return (ushort)((u + 0x7fffu + ((u >> 16) & 1u)) >> 16);
}
__device__ inline float b2f(ushort b) { return __uint_as_float(((uint)b) << 16); }

// ---------------- CSR build ----------------

__global__ void hist_kernel(const int* __restrict__ dst, int* __restrict__ counts, int E) {
    int e = blockIdx.x * blockDim.x + threadIdx.x;
    if (e < E) atomicAdd(&counts[dst[e]], 1);
}

__global__ __launch_bounds__(1024) void scan_kernel(const int* __restrict__ counts,
                                                    int* __restrict__ offsets, int n) {
    __shared__ int sdata[1024];
    __shared__ int srun;
    if (threadIdx.x == 0) srun = 0;
    __syncthreads();
    for (int base = 0; base < n; base += 1024) {
        int i = base + (int)threadIdx.x;
        int v = (i < n) ? counts[i] : 0;
        sdata[threadIdx.x] = v;
        __syncthreads();
        for (int off = 1; off < 1024; off <<= 1) {
            int t = (threadIdx.x >= off) ? sdata[threadIdx.x - off] : 0;
            __syncthreads();
            sdata[threadIdx.x] += t;
            __syncthreads();
        }
        int incl = sdata[threadIdx.x];
        int run = srun;
        if (i < n) offsets[i + 1] = run + incl;
        __syncthreads();
        if (threadIdx.x == 1023) srun = run + incl;
        __syncthreads();
    }
    if (threadIdx.x == 0) offsets[0] = 0;
}

__global__ void scatter_kernel(const int* __restrict__ src, const int* __restrict__ dst,
                               const int* __restrict__ et, int* __restrict__ cursor,
                               int* __restrict__ src_s, int* __restrict__ dst_s,
                               int* __restrict__ et_s, int E) {
    int e = blockIdx.x * blockDim.x + threadIdx.x;
    if (e >= E) return;
    int d = dst[e];
    int pos = atomicAdd(&cursor[d], 1);
    src_s[pos] = src[e];
    dst_s[pos] = d;
    et_s[pos]  = et[e];
}

// ---------------- weight prep: W[K][N] f32 -> Wt[N][K] bf16 ----------------

__global__ void wprep(const float* __restrict__ W, ushort* __restrict__ Wt, int K, int N) {
    int i = blockIdx.x * blockDim.x + threadIdx.x;
    if (i >= K * N) return;
    int k = i / N, n = i % N;
    Wt[(long)n * K + k] = f2b(W[i]);
}

// ---------------- bf16 MFMA GEMM: C[M,N] = A[M,K] @ Bt[N,K]^T ----------------

template<bool F32OUT>
__global__ __launch_bounds__(256) void gemm_bf16(const ushort* __restrict__ A,
                                                 const ushort* __restrict__ Bt,
                                                 float* __restrict__ Cf,
                                                 ushort* __restrict__ Cb,
                                                 int M, int N, int K) {
    __shared__ ushort As[128][40];
    __shared__ ushort Bs[128][40];
    int bm = blockIdx.y * 128, bn = blockIdx.x * 128;
    int tid = threadIdx.x;
    int wave = tid >> 6, lane = tid & 63;
    int wm = (wave >> 1) * 64, wn = (wave & 1) * 64;
    floatx4 acc[4][4] = {};
    for (int k0 = 0; k0 < K; k0 += 32) {
#pragma unroll
        for (int it = 0; it < 2; ++it) {
            int idx = (tid + it * 256) * 8;
            int r = idx >> 5, c = idx & 31;
            int gr = bm + r;
            uint4 va = {0u, 0u, 0u, 0u};
            if (gr < M) va = *reinterpret_cast<const uint4*>(&A[(long)gr * K + k0 + c]);
            *reinterpret_cast<uint4*>(&As[r][c]) = va;
            uint4 vb = *reinterpret_cast<const uint4*>(&Bt[(long)(bn + r) * K + k0 + c]);
            *reinterpret_cast<uint4*>(&Bs[r][c]) = vb;
        }
        __syncthreads();
        int lr = lane & 15, lk = (lane >> 4) * 8;
        short8v af[4], bfr[4];
#pragma unroll
        for (int i = 0; i < 4; ++i)
            af[i] = *reinterpret_cast<const short8v*>(&As[wm + i * 16 + lr][lk]);
#pragma unroll
        for (int j = 0; j < 4; ++j)
            bfr[j] = *reinterpret_cast<const short8v*>(&Bs[wn + j * 16 + lr][lk]);
#pragma unroll
        for (int i = 0; i < 4; ++i)
#pragma unroll
            for (int j = 0; j < 4; ++j)
                acc[i][j] = __builtin_amdgcn_mfma_f32_16x16x32_bf16(af[i], bfr[j], acc[i][j], 0, 0, 0);
        __syncthreads();
    }
    int col = lane & 15, rbase = (lane >> 4) * 4;
#pragma unroll
    for (int i = 0; i < 4; ++i) {
#pragma unroll
        for (int r = 0; r < 4; ++r) {
            int gm = bm + wm + i * 16 + rbase + r;
            if (gm >= M) continue;
#pragma unroll
            for (int j = 0; j < 4; ++j) {
                int gn = bn + wn + j * 16 + col;
                float v = acc[i][j][r];
                if (F32OUT) Cf[(long)gm * N + gn] = v;
                else Cb[(long)gm * N + gn] = f2b(v);
            }
        }
    }
}

// ---------------- input FC (f32 compute, bf16 out): C[M,64] = A@W + b ----------------

__global__ __launch_bounds__(256) void matmul64_fc(const float* __restrict__ A,
                                                   const float* __restrict__ W,
                                                   const float* __restrict__ bias,
                                                   ushort* __restrict__ C,
                                                   int M, int K, int N) {
    __shared__ float As[16][68];
    __shared__ float Bs[16][68];
    int bm = blockIdx.y * 64, bn = blockIdx.x * 64;
    int tx = threadIdx.x % 16, ty = threadIdx.x / 16;
    float acc[4][4] = {};
    for (int k0 = 0; k0 < K; k0 += 16) {
        for (int i = threadIdx.x; i < 64 * 16; i += 256) {
            int mm = i / 16, kk = i % 16;
            int gm = bm + mm;
            As[kk][mm] = (gm < M) ? A[(long)gm * K + k0 + kk] : 0.f;
        }
        for (int i = threadIdx.x; i < 16 * 64; i += 256) {
            int kk = i / 64, nn = i % 64;
            Bs[kk][nn] = W[(long)(k0 + kk) * N + bn + nn];
        }
        __syncthreads();
#pragma unroll
        for (int kk = 0; kk < 16; ++kk) {
            float a[4], b[4];
#pragma unroll
            for (int i = 0; i < 4; ++i) a[i] = As[kk][ty * 4 + i];
#pragma unroll
            for (int j = 0; j < 4; ++j) b[j] = Bs[kk][tx * 4 + j];
#pragma unroll
            for (int i = 0; i < 4; ++i)
#pragma unroll
                for (int j = 0; j < 4; ++j) acc[i][j] += a[i] * b[j];
        }
        __syncthreads();
    }
#pragma unroll
    for (int i = 0; i < 4; ++i) {
        int gm = bm + ty * 4 + i;
        if (gm >= M) continue;
#pragma unroll
        for (int j = 0; j < 4; ++j) {
            int gn = bn + tx * 4 + j;
            C[(long)gm * N + gn] = f2b(acc[i][j] + bias[gn]);
        }
    }
}

// ---------------- small N=16 matmul, bf16 A: C[M,16] = A[M,K] @ W[K,16] (+=) ----------------

template<bool ACC>
__global__ __launch_bounds__(256) void matmul_n16b(const ushort* __restrict__ A,
                                                   const float* __restrict__ W,
                                                   float* __restrict__ C, int M, int K) {
    __shared__ float Ws[256 * 16];
    for (int i = threadIdx.x; i < K * 16; i += 256) Ws[i] = W[i];
    __syncthreads();
    int m = blockIdx.x * 16 + threadIdx.x / 16;
    int nn = threadIdx.x % 16;
    if (m >= M) return;
    float s = 0.f;
    for (int k8 = 0; k8 < K / 8; ++k8) {
        uint4 v = *reinterpret_cast<const uint4*>(&A[(long)m * K + k8 * 8]);
        const uint* vp = reinterpret_cast<const uint*>(&v);
#pragma unroll
        for (int q = 0; q < 4; ++q) {
            uint w2 = vp[q];
            float f0 = __uint_as_float((w2 & 0xffffu) << 16);
            float f1 = __uint_as_float(w2 & 0xffff0000u);
            int k = k8 * 8 + q * 2;
            s += f0 * Ws[(k + 0) * 16 + nn] + f1 * Ws[(k + 1) * 16 + nn];
        }
    }
    if (ACC) s += C[(long)m * 16 + nn];
    C[(long)m * 16 + nn] = s;
}

// ---------------- attention pieces ----------------

template<int H, int OUT>
__global__ void attn_lr(const float* __restrict__ feat, const float* __restrict__ al,
                        const float* __restrict__ ar, float* __restrict__ el,
                        float* __restrict__ er, int N) {
    int gid = blockIdx.x * blockDim.x + threadIdx.x;
    int n = gid / H, h = gid % H;
    if (n >= N) return;
    const float* fr = feat + (long)n * H * OUT + h * OUT;
    float sl = 0.f, sr = 0.f;
#pragma unroll
    for (int o = 0; o < OUT; ++o) {
        float f = fr[o];
        sl += f * al[h * OUT + o];
        sr += f * ar[h * OUT + o];
    }
    el[n * H + h] = sl;
    er[n * H + h] = sr;
}

// et_att[t,h] = sum_d (eemb[t] @ We)[h*64+d] * ae[h,d]
// grid: 6 blocks (one per etype); block: H*64 threads; wave w == head w.
template<int H>
__global__ __launch_bounds__(H * 64) void etype_att(const float* __restrict__ eemb,
                                                    const float* __restrict__ We,
                                                    const float* __restrict__ ae,
                                                    float* __restrict__ out) {
    __shared__ float es[64];
    int t = blockIdx.x;
    int j = threadIdx.x;               // j = h*64 + d
    if (j < 64) es[j] = eemb[t * 64 + j];
    __syncthreads();
    float wsum = 0.f;
#pragma unroll 8
    for (int k = 0; k < 64; ++k) wsum += es[k] * We[k * (H * 64) + j];
    float v = wsum * ae[j];
#pragma unroll
    for (int off = 32; off > 0; off >>= 1) v += __shfl_down(v, off, 64);
    if ((j & 63) == 0) out[t * H + (j >> 6)] = v;
}

template<int H>
__global__ void edge_logits(const float* __restrict__ el, const float* __restrict__ er,
                            const float* __restrict__ etatt,
                            const int* __restrict__ src_s, const int* __restrict__ dst_s,
                            const int* __restrict__ et_s, float* __restrict__ e_csr, int E) {
    int p = blockIdx.x * blockDim.x + threadIdx.x;
    if (p >= E) return;
    int s = src_s[p], d = dst_s[p], t = et_s[p];
#pragma unroll
    for (int h = 0; h < H; ++h) {
        float v = el[s * H + h] + er[d * H + h] + etatt[t * H + h];
        v = v > 0.f ? v : SLOPE * v;
        e_csr[(long)p * H + h] = v;
    }
}

template<int H, bool BLEND, bool SAVE>
__global__ void edge_softmax(const int* __restrict__ offsets, float* __restrict__ e_csr,
                             const float* __restrict__ a0, float* __restrict__ a0_out, int N) {
    int gid = blockIdx.x * blockDim.x + threadIdx.x;
    int d = gid / H, h = gid % H;
    if (d >= N) return;
    int lo = offsets[d], hi = offsets[d + 1];
    float m = -INFINITY;
    for (int p = lo; p < hi; ++p) m = fmaxf(m, e_csr[(long)p * H + h]);
    float ssum = 0.f;
    for (int p = lo; p < hi; ++p) ssum += expf(e_csr[(long)p * H + h] - m);
    float inv = (ssum > 0.f) ? 1.0f / ssum : 0.f;
    for (int p = lo; p < hi; ++p) {
        float a = expf(e_csr[(long)p * H + h] - m) * inv;
        if (BLEND) a = a * (1.0f - ALPHA) + a0[(long)p * H + h] * ALPHA;
        e_csr[(long)p * H + h] = a;
        if (SAVE) a0_out[(long)p * H + h] = a;
    }
}

// rst[d,:] = (res?) + sum_p a[p,h] * feat[src_p,:]; optional ELU; f32 or bf16 out
template<int H, int OUT, bool RESIN, bool ELU, bool BF16OUT>
__global__ __launch_bounds__(256) void aggregate(const int* __restrict__ offsets,
                                                 const int* __restrict__ src_s,
                                                 const float* __restrict__ a_csr,
                                                 const float* __restrict__ feat,
                                                 const ushort* __restrict__ resin,
                                                 float* __restrict__ outf,
                                                 ushort* __restrict__ outb, int N) {
    constexpr int CH = H * OUT;
    constexpr int TPD = CH / 4;
    int tid = blockIdx.x * blockDim.x + threadIdx.x;
    int d = tid / TPD;
    int t = tid % TPD;
    if (d >= N) return;
    int lo = offsets[d], hi = offsets[d + 1];
    int c = t * 4;
    int h = c / OUT;
    float4 acc = {0.f, 0.f, 0.f, 0.f};
    if (RESIN) {
        ushort4 r = *reinterpret_cast<const ushort4*>(&resin[(long)d * CH + c]);
        acc.x = b2f(r.x); acc.y = b2f(r.y); acc.z = b2f(r.z); acc.w = b2f(r.w);
    }
    for (int p = lo; p < hi; ++p) {
        int s = src_s[p];
        float a = a_csr[(long)p * H + h];
        float4 f = *reinterpret_cast<const float4*>(&feat[(long)s * CH + c]);
        acc.x += f.x * a;
        acc.y += f.y * a;
        acc.z += f.z * a;
        acc.w += f.w * a;
    }
    if (ELU) {
        acc.x = acc.x > 0.f ? acc.x : expf(acc.x) - 1.f;
        acc.y = acc.y > 0.f ? acc.y : expf(acc.y) - 1.f;
        acc.z = acc.z > 0.f ? acc.z : expf(acc.z) - 1.f;
        acc.w = acc.w > 0.f ? acc.w : expf(acc.w) - 1.f;
    }
    if (BF16OUT) {
        ushort4 o = {f2b(acc.x), f2b(acc.y), f2b(acc.z), f2b(acc.w)};
        *reinterpret_cast<ushort4*>(&outb[(long)d * CH + c]) = o;
    } else {
        *reinterpret_cast<float4*>(&outf[(long)d * CH + c]) = acc;
    }
}

// ---------------- launch ----------------

extern "C" void kernel_launch(void* const* d_in, const int* in_sizes, int n_in,
                              void* d_out, int out_size, void* d_ws, size_t ws_size,
                              hipStream_t stream) {
    const float* x0   = (const float*)d_in[0];
    const float* x1   = (const float*)d_in[1];
    const float* x2   = (const float*)d_in[2];
    const float* fcw0 = (const float*)d_in[3];
    const float* fcb0 = (const float*)d_in[4];
    const float* fcw1 = (const float*)d_in[5];
    const float* fcb1 = (const float*)d_in[6];
    const float* fcw2 = (const float*)d_in[7];
    const float* fcb2 = (const float*)d_in[8];
    const float* W0   = (const float*)d_in[9];
    const float* We0  = (const float*)d_in[10];
    const float* eemb0= (const float*)d_in[11];
    const float* al0  = (const float*)d_in[12];
    const float* ar0  = (const float*)d_in[13];
    const float* ae0  = (const float*)d_in[14];
    const float* W1   = (const float*)d_in[15];
    const float* We1  = (const float*)d_in[16];
    const float* eemb1= (const float*)d_in[17];
    const float* al1  = (const float*)d_in[18];
    const float* ar1  = (const float*)d_in[19];
    const float* ae1  = (const float*)d_in[20];
    const float* resW1= (const float*)d_in[21];
    const float* W2   = (const float*)d_in[22];
    const float* We2  = (const float*)d_in[23];
    const float* eemb2= (const float*)d_in[24];
    const float* al2  = (const float*)d_in[25];
    const float* ar2  = (const float*)d_in[26];
    const float* ae2  = (const float*)d_in[27];
    const float* resW2= (const float*)d_in[28];
    const int* src    = (const int*)d_in[29];
    const int* dst    = (const int*)d_in[30];
    const int* etype  = (const int*)d_in[31];

    const int n0 = in_sizes[0] / 128;
    const int n1 = in_sizes[1] / 256;
    const int n2 = in_sizes[2] / 64;
    const int N  = n0 + n1 + n2;
    const int E  = in_sizes[29];

    char* w = (char*)d_ws;
    auto alloc = [&](size_t bytes) {
        char* p = w;
        w += (bytes + 255) & ~(size_t)255;
        return p;
    };
    int*    counts  = (int*)alloc((size_t)N * 4);
    int*    offsets = (int*)alloc((size_t)(N + 1) * 4);
    int*    cursor  = (int*)alloc((size_t)N * 4);
    int*    src_s   = (int*)alloc((size_t)E * 4);
    int*    dst_s   = (int*)alloc((size_t)E * 4);
    int*    et_s    = (int*)alloc((size_t)E * 4);
    float*  e_csr   = (float*)alloc((size_t)E * 8 * 4);
    ushort* a0_csr  = (ushort*)alloc((size_t)E * 8 * 4);  // f32 a0 (layer0) -> reused as bf16 h2res
    ushort* h0bf    = (ushort*)alloc((size_t)N * 64 * 2);
    float*  feat    = (float*)alloc((size_t)N * 256 * 4);
    ushort* h1bf    = (ushort*)alloc((size_t)N * 256 * 2);
    ushort* h2bf    = (ushort*)alloc((size_t)N * 256 * 2);
    float*  el      = (float*)alloc((size_t)N * 8 * 4);
    float*  er      = (float*)alloc((size_t)N * 8 * 4);
    float*  etatt   = (float*)alloc(6 * 8 * 4);
    ushort* Wt0     = (ushort*)alloc((size_t)256 * 64 * 2);
    ushort* Wt1     = (ushort*)alloc((size_t)256 * 256 * 2);
    ushort* WtR     = (ushort*)alloc((size_t)256 * 256 * 2);
    float*  feat2   = (float*)alloc((size_t)N * 16 * 4);
    float*  a0f     = (float*)a0_csr;   // f32 view for layer-0 attention save
    ushort* h2res   = a0_csr;           // bf16 view, reused AFTER layer-1 softmax consumed a0
    float*  out     = (float*)d_out;

    const int TB = 256;
    int eb = (E + TB - 1) / TB;

    // ---- CSR build ----
    hipMemsetAsync(counts, 0, (size_t)N * 4, stream);
    hist_kernel<<<eb, TB, 0, stream>>>(dst, counts, E);
    scan_kernel<<<1, 1024, 0, stream>>>(counts, offsets, N);
    hipMemcpyAsync(cursor, offsets, (size_t)N * 4, hipMemcpyDeviceToDevice, stream);
    scatter_kernel<<<eb, TB, 0, stream>>>(src, dst, etype, cursor, src_s, dst_s, et_s, E);

    // ---- weight prep ----
    wprep<<<(64 * 256 + TB - 1) / TB, TB, 0, stream>>>(W0, Wt0, 64, 256);
    wprep<<<(256 * 256 + TB - 1) / TB, TB, 0, stream>>>(W1, Wt1, 256, 256);
    wprep<<<(256 * 256 + TB - 1) / TB, TB, 0, stream>>>(resW1, WtR, 256, 256);

    // ---- input FC: h0bf = concat(x_i @ fcw_i + fcb_i) ----
    {
        dim3 g0(1, (n0 + 63) / 64);
        matmul64_fc<<<g0, TB, 0, stream>>>(x0, fcw0, fcb0, h0bf, n0, 128, 64);
        dim3 g1(1, (n1 + 63) / 64);
        matmul64_fc<<<g1, TB, 0, stream>>>(x1, fcw1, fcb1, h0bf + (long)n0 * 64, n1, 256, 64);
        dim3 g2(1, (n2 + 63) / 64);
        matmul64_fc<<<g2, TB, 0, stream>>>(x2, fcw2, fcb2, h0bf + (long)(n0 + n1) * 64, n2, 64, 64);
    }

    int nb_nh8 = (N * 8 + TB - 1) / TB;
    int nb_agg = (N * 64 + TB - 1) / TB;
    dim3 gg(256 / 128, (N + 127) / 128);

    // ---- layer 0 ----
    {
        gemm_bf16<true><<<gg, TB, 0, stream>>>(h0bf, Wt0, feat, nullptr, N, 256, 64);
        attn_lr<8, 32><<<nb_nh8, TB, 0, stream>>>(feat, al0, ar0, el, er, N);
        etype_att<8><<<6, 512, 0, stream>>>(eemb0, We0, ae0, etatt);
        edge_logits<8><<<eb, TB, 0, stream>>>(el, er, etatt, src_s, dst_s, et_s, e_csr, E);
        edge_softmax<8, false, true><<<nb_nh8, TB, 0, stream>>>(offsets, e_csr, nullptr, a0f, N);
        aggregate<8, 32, false, true, true><<<nb_agg, TB, 0, stream>>>(
            offsets, src_s, e_csr, feat, nullptr, nullptr, h1bf, N);
    }

    // ---- layer 1 ----
    {
        gemm_bf16<true><<<gg, TB, 0, stream>>>(h1bf, Wt1, feat, nullptr, N, 256, 256);
        attn_lr<8, 32><<<nb_nh8, TB, 0, stream>>>(feat, al1, ar1, el, er, N);
        etype_att<8><<<6, 512, 0, stream>>>(eemb1, We1, ae1, etatt);
        edge_logits<8><<<eb, TB, 0, stream>>>(el, er, etatt, src_s, dst_s, et_s, e_csr, E);
        edge_softmax<8, true, false><<<nb_nh8, TB, 0, stream>>>(offsets, e_csr, a0f, nullptr, N);
        gemm_bf16<false><<<gg, TB, 0, stream>>>(h1bf, WtR, nullptr, h2res, N, 256, 256);
        aggregate<8, 32, true, true, true><<<nb_agg, TB, 0, stream>>>(
            offsets, src_s, e_csr, feat, h2res, nullptr, h2bf, N);
    }

    // ---- layer 2 (H=1, OUT=16, residual, no activation) ----
    {
        matmul_n16b<false><<<(N + 15) / 16, TB, 0, stream>>>(h2bf, W2, feat2, N, 256);
        int nb_nh1 = (N + TB - 1) / TB;
        attn_lr<1, 16><<<nb_nh1, TB, 0, stream>>>(feat2, al2, ar2, el, er, N);
        etype_att<1><<<6, 64, 0, stream>>>(eemb2, We2, ae2, etatt);
        edge_logits<1><<<eb, TB, 0, stream>>>(el, er, etatt, src_s, dst_s, et_s, e_csr, E);
        edge_softmax<1, false, false><<<nb_nh1, TB, 0, stream>>>(offsets, e_csr, nullptr, nullptr, N);
        int nb_agg2 = (N * 4 + TB - 1) / TB;
        aggregate<1, 16, false, false, false><<<nb_agg2, TB, 0, stream>>>(
            offsets, src_s, e_csr, feat2, nullptr, out, nullptr, N);
        matmul_n16b<true><<<(N + 15) / 16, TB, 0, stream>>>(h2bf, resW2, out, N, 256);
    }
}

// Round 4
// 704.937 us; speedup vs baseline: 1.9162x; 1.1050x over previous
//
#include <hip/hip_runtime.h>
#include <hip/hip_bf16.h>

#define ALPHA 0.05f
#define SLOPE 0.2f

typedef __attribute__((ext_vector_type(8))) short short8v;
typedef __attribute__((ext_vector_type(4))) float floatx4;

__device__ inline ushort f2b(float f) {
    uint u = __float_as_uint(f);
    return (ushort)((u + 0x7fffu + ((u >> 16) & 1u)) >> 16);
}
__device__ inline float b2f(ushort b) { return __uint_as_float(((uint)b) << 16); }

// ---------------- CSR build ----------------

__global__ void hist_kernel(const int* __restrict__ dst, int* __restrict__ counts, int E) {
    int e = blockIdx.x * blockDim.x + threadIdx.x;
    if (e < E) atomicAdd(&counts[dst[e]], 1);
}

__global__ __launch_bounds__(1024) void scan_kernel(const int* __restrict__ counts,
                                                    int* __restrict__ offsets, int n) {
    __shared__ int sdata[1024];
    __shared__ int srun;
    if (threadIdx.x == 0) srun = 0;
    __syncthreads();
    for (int base = 0; base < n; base += 1024) {
        int i = base + (int)threadIdx.x;
        int v = (i < n) ? counts[i] : 0;
        sdata[threadIdx.x] = v;
        __syncthreads();
        for (int off = 1; off < 1024; off <<= 1) {
            int t = (threadIdx.x >= off) ? sdata[threadIdx.x - off] : 0;
            __syncthreads();
            sdata[threadIdx.x] += t;
            __syncthreads();
        }
        int incl = sdata[threadIdx.x];
        int run = srun;
        if (i < n) offsets[i + 1] = run + incl;
        __syncthreads();
        if (threadIdx.x == 1023) srun = run + incl;
        __syncthreads();
    }
    if (threadIdx.x == 0) offsets[0] = 0;
}

__global__ void scatter_kernel(const int* __restrict__ src, const int* __restrict__ dst,
                               const int* __restrict__ et, int* __restrict__ cursor,
                               int* __restrict__ src_s, int* __restrict__ dst_s,
                               int* __restrict__ et_s, int E) {
    int e = blockIdx.x * blockDim.x + threadIdx.x;
    if (e >= E) return;
    int d = dst[e];
    int pos = atomicAdd(&cursor[d], 1);
    src_s[pos] = src[e];
    dst_s[pos] = d;
    et_s[pos]  = et[e];
}

// ---------------- weight prep: W[K][N] f32 -> Wt[N][K] bf16 ----------------

__global__ void wprep(const float* __restrict__ W, ushort* __restrict__ Wt, int K, int N) {
    int i = blockIdx.x * blockDim.x + threadIdx.x;
    if (i >= K * N) return;
    int k = i / N, n = i % N;
    Wt[(long)n * K + k] = f2b(W[i]);
}

// ---------------- bf16 MFMA GEMM: C[M,N] = A[M,K] @ Bt[N,K]^T ----------------

template<bool F32OUT>
__global__ __launch_bounds__(256) void gemm_bf16(const ushort* __restrict__ A,
                                                 const ushort* __restrict__ Bt,
                                                 float* __restrict__ Cf,
                                                 ushort* __restrict__ Cb,
                                                 int M, int N, int K) {
    __shared__ ushort As[128][40];
    __shared__ ushort Bs[128][40];
    int bm = blockIdx.y * 128, bn = blockIdx.x * 128;
    int tid = threadIdx.x;
    int wave = tid >> 6, lane = tid & 63;
    int wm = (wave >> 1) * 64, wn = (wave & 1) * 64;
    floatx4 acc[4][4] = {};
    for (int k0 = 0; k0 < K; k0 += 32) {
#pragma unroll
        for (int it = 0; it < 2; ++it) {
            int idx = (tid + it * 256) * 8;
            int r = idx >> 5, c = idx & 31;
            int gr = bm + r;
            uint4 va = {0u, 0u, 0u, 0u};
            if (gr < M) va = *reinterpret_cast<const uint4*>(&A[(long)gr * K + k0 + c]);
            *reinterpret_cast<uint4*>(&As[r][c]) = va;
            uint4 vb = *reinterpret_cast<const uint4*>(&Bt[(long)(bn + r) * K + k0 + c]);
            *reinterpret_cast<uint4*>(&Bs[r][c]) = vb;
        }
        __syncthreads();
        int lr = lane & 15, lk = (lane >> 4) * 8;
        short8v af[4], bfr[4];
#pragma unroll
        for (int i = 0; i < 4; ++i)
            af[i] = *reinterpret_cast<const short8v*>(&As[wm + i * 16 + lr][lk]);
#pragma unroll
        for (int j = 0; j < 4; ++j)
            bfr[j] = *reinterpret_cast<const short8v*>(&Bs[wn + j * 16 + lr][lk]);
#pragma unroll
        for (int i = 0; i < 4; ++i)
#pragma unroll
            for (int j = 0; j < 4; ++j)
                acc[i][j] = __builtin_amdgcn_mfma_f32_16x16x32_bf16(af[i], bfr[j], acc[i][j], 0, 0, 0);
        __syncthreads();
    }
    int col = lane & 15, rbase = (lane >> 4) * 4;
#pragma unroll
    for (int i = 0; i < 4; ++i) {
#pragma unroll
        for (int r = 0; r < 4; ++r) {
            int gm = bm + wm + i * 16 + rbase + r;
            if (gm >= M) continue;
#pragma unroll
            for (int j = 0; j < 4; ++j) {
                int gn = bn + wn + j * 16 + col;
                float v = acc[i][j][r];
                if (F32OUT) Cf[(long)gm * N + gn] = v;
                else Cb[(long)gm * N + gn] = f2b(v);
            }
        }
    }
}

// ---------------- input FC (f32 compute, bf16 out): C[M,64] = A@W + b ----------------

__global__ __launch_bounds__(256) void matmul64_fc(const float* __restrict__ A,
                                                   const float* __restrict__ W,
                                                   const float* __restrict__ bias,
                                                   ushort* __restrict__ C,
                                                   int M, int K, int N) {
    __shared__ float As[16][68];
    __shared__ float Bs[16][68];
    int bm = blockIdx.y * 64, bn = blockIdx.x * 64;
    int tx = threadIdx.x % 16, ty = threadIdx.x / 16;
    float acc[4][4] = {};
    for (int k0 = 0; k0 < K; k0 += 16) {
        for (int i = threadIdx.x; i < 64 * 16; i += 256) {
            int mm = i / 16, kk = i % 16;
            int gm = bm + mm;
            As[kk][mm] = (gm < M) ? A[(long)gm * K + k0 + kk] : 0.f;
        }
        for (int i = threadIdx.x; i < 16 * 64; i += 256) {
            int kk = i / 64, nn = i % 64;
            Bs[kk][nn] = W[(long)(k0 + kk) * N + bn + nn];
        }
        __syncthreads();
#pragma unroll
        for (int kk = 0; kk < 16; ++kk) {
            float a[4], b[4];
#pragma unroll
            for (int i = 0; i < 4; ++i) a[i] = As[kk][ty * 4 + i];
#pragma unroll
            for (int j = 0; j < 4; ++j) b[j] = Bs[kk][tx * 4 + j];
#pragma unroll
            for (int i = 0; i < 4; ++i)
#pragma unroll
                for (int j = 0; j < 4; ++j) acc[i][j] += a[i] * b[j];
        }
        __syncthreads();
    }
#pragma unroll
    for (int i = 0; i < 4; ++i) {
        int gm = bm + ty * 4 + i;
        if (gm >= M) continue;
#pragma unroll
        for (int j = 0; j < 4; ++j) {
            int gn = bn + tx * 4 + j;
            C[(long)gm * N + gn] = f2b(acc[i][j] + bias[gn]);
        }
    }
}

// ---------------- small N=16 matmul, bf16 A: C[M,16] = A[M,K] @ W[K,16] (+=) ----------------

template<bool ACC>
__global__ __launch_bounds__(256) void matmul_n16b(const ushort* __restrict__ A,
                                                   const float* __restrict__ W,
                                                   float* __restrict__ C, int M, int K) {
    __shared__ float Ws[256 * 16];
    for (int i = threadIdx.x; i < K * 16; i += 256) Ws[i] = W[i];
    __syncthreads();
    int m = blockIdx.x * 16 + threadIdx.x / 16;
    int nn = threadIdx.x % 16;
    if (m >= M) return;
    float s = 0.f;
    for (int k8 = 0; k8 < K / 8; ++k8) {
        uint4 v = *reinterpret_cast<const uint4*>(&A[(long)m * K + k8 * 8]);
        const uint* vp = reinterpret_cast<const uint*>(&v);
#pragma unroll
        for (int q = 0; q < 4; ++q) {
            uint w2 = vp[q];
            float f0 = __uint_as_float((w2 & 0xffffu) << 16);
            float f1 = __uint_as_float(w2 & 0xffff0000u);
            int k = k8 * 8 + q * 2;
            s += f0 * Ws[(k + 0) * 16 + nn] + f1 * Ws[(k + 1) * 16 + nn];
        }
    }
    if (ACC) s += C[(long)m * 16 + nn];
    C[(long)m * 16 + nn] = s;
}

// ---------------- attention pieces ----------------

// f32-feat version (layer 2)
template<int H, int OUT>
__global__ void attn_lr(const float* __restrict__ feat, const float* __restrict__ al,
                        const float* __restrict__ ar, float* __restrict__ el,
                        float* __restrict__ er, int N) {
    int gid = blockIdx.x * blockDim.x + threadIdx.x;
    int n = gid / H, h = gid % H;
    if (n >= N) return;
    const float* fr = feat + (long)n * H * OUT + h * OUT;
    float sl = 0.f, sr = 0.f;
#pragma unroll
    for (int o = 0; o < OUT; ++o) {
        float f = fr[o];
        sl += f * al[h * OUT + o];
        sr += f * ar[h * OUT + o];
    }
    el[n * H + h] = sl;
    er[n * H + h] = sr;
}

// bf16-feat version (layers 0/1)
template<int H, int OUT>
__global__ void attn_lr_b(const ushort* __restrict__ feat, const float* __restrict__ al,
                          const float* __restrict__ ar, float* __restrict__ el,
                          float* __restrict__ er, int N) {
    int gid = blockIdx.x * blockDim.x + threadIdx.x;
    int n = gid / H, h = gid % H;
    if (n >= N) return;
    const ushort* fr = feat + (long)n * H * OUT + h * OUT;
    float sl = 0.f, sr = 0.f;
#pragma unroll
    for (int q = 0; q < OUT / 8; ++q) {
        uint4 v = *reinterpret_cast<const uint4*>(&fr[q * 8]);
        const uint* vp = reinterpret_cast<const uint*>(&v);
#pragma unroll
        for (int i = 0; i < 4; ++i) {
            float f0 = __uint_as_float((vp[i] & 0xffffu) << 16);
            float f1 = __uint_as_float(vp[i] & 0xffff0000u);
            int o = q * 8 + i * 2;
            sl += f0 * al[h * OUT + o] + f1 * al[h * OUT + o + 1];
            sr += f0 * ar[h * OUT + o] + f1 * ar[h * OUT + o + 1];
        }
    }
    el[n * H + h] = sl;
    er[n * H + h] = sr;
}

// et_att[t,h] = sum_d (eemb[t] @ We)[h*64+d] * ae[h,d]
template<int H>
__global__ __launch_bounds__(H * 64) void etype_att(const float* __restrict__ eemb,
                                                    const float* __restrict__ We,
                                                    const float* __restrict__ ae,
                                                    float* __restrict__ out) {
    __shared__ float es[64];
    int t = blockIdx.x;
    int j = threadIdx.x;               // j = h*64 + d
    if (j < 64) es[j] = eemb[t * 64 + j];
    __syncthreads();
    float wsum = 0.f;
#pragma unroll 8
    for (int k = 0; k < 64; ++k) wsum += es[k] * We[k * (H * 64) + j];
    float v = wsum * ae[j];
#pragma unroll
    for (int off = 32; off > 0; off >>= 1) v += __shfl_down(v, off, 64);
    if ((j & 63) == 0) out[t * H + (j >> 6)] = v;
}

template<int H>
__global__ void edge_logits(const float* __restrict__ el, const float* __restrict__ er,
                            const float* __restrict__ etatt,
                            const int* __restrict__ src_s, const int* __restrict__ dst_s,
                            const int* __restrict__ et_s, float* __restrict__ e_csr, int E) {
    int p = blockIdx.x * blockDim.x + threadIdx.x;
    if (p >= E) return;
    int s = src_s[p], d = dst_s[p], t = et_s[p];
#pragma unroll
    for (int h = 0; h < H; ++h) {
        float v = el[s * H + h] + er[d * H + h] + etatt[t * H + h];
        v = v > 0.f ? v : SLOPE * v;
        e_csr[(long)p * H + h] = v;
    }
}

template<int H, bool BLEND, bool SAVE>
__global__ void edge_softmax(const int* __restrict__ offsets, float* __restrict__ e_csr,
                             const float* __restrict__ a0, float* __restrict__ a0_out, int N) {
    int gid = blockIdx.x * blockDim.x + threadIdx.x;
    int d = gid / H, h = gid % H;
    if (d >= N) return;
    int lo = offsets[d], hi = offsets[d + 1];
    float m = -INFINITY;
    for (int p = lo; p < hi; ++p) m = fmaxf(m, e_csr[(long)p * H + h]);
    float ssum = 0.f;
    for (int p = lo; p < hi; ++p) ssum += expf(e_csr[(long)p * H + h] - m);
    float inv = (ssum > 0.f) ? 1.0f / ssum : 0.f;
    for (int p = lo; p < hi; ++p) {
        float a = expf(e_csr[(long)p * H + h] - m) * inv;
        if (BLEND) a = a * (1.0f - ALPHA) + a0[(long)p * H + h] * ALPHA;
        e_csr[(long)p * H + h] = a;
        if (SAVE) a0_out[(long)p * H + h] = a;
    }
}

// rst[d,:] = (res?) + sum_p a[p,h] * feat[src_p,:]; optional ELU; f32/bf16 in and out
template<int H, int OUT, bool RESIN, bool ELU, bool BF16OUT, bool BF16IN>
__global__ __launch_bounds__(256) void aggregate(const int* __restrict__ offsets,
                                                 const int* __restrict__ src_s,
                                                 const float* __restrict__ a_csr,
                                                 const float* __restrict__ featf,
                                                 const ushort* __restrict__ featb,
                                                 const ushort* __restrict__ resin,
                                                 float* __restrict__ outf,
                                                 ushort* __restrict__ outb, int N) {
    constexpr int CH = H * OUT;
    constexpr int TPD = CH / 4;
    int tid = blockIdx.x * blockDim.x + threadIdx.x;
    int d = tid / TPD;
    int t = tid % TPD;
    if (d >= N) return;
    int lo = offsets[d], hi = offsets[d + 1];
    int c = t * 4;
    int h = c / OUT;
    float4 acc = {0.f, 0.f, 0.f, 0.f};
    if (RESIN) {
        ushort4 r = *reinterpret_cast<const ushort4*>(&resin[(long)d * CH + c]);
        acc.x = b2f(r.x); acc.y = b2f(r.y); acc.z = b2f(r.z); acc.w = b2f(r.w);
    }
    for (int p = lo; p < hi; ++p) {
        int s = src_s[p];
        float a = a_csr[(long)p * H + h];
        float4 f;
        if (BF16IN) {
            ushort4 fb = *reinterpret_cast<const ushort4*>(&featb[(long)s * CH + c]);
            f.x = b2f(fb.x); f.y = b2f(fb.y); f.z = b2f(fb.z); f.w = b2f(fb.w);
        } else {
            f = *reinterpret_cast<const float4*>(&featf[(long)s * CH + c]);
        }
        acc.x += f.x * a;
        acc.y += f.y * a;
        acc.z += f.z * a;
        acc.w += f.w * a;
    }
    if (ELU) {
        acc.x = acc.x > 0.f ? acc.x : expf(acc.x) - 1.f;
        acc.y = acc.y > 0.f ? acc.y : expf(acc.y) - 1.f;
        acc.z = acc.z > 0.f ? acc.z : expf(acc.z) - 1.f;
        acc.w = acc.w > 0.f ? acc.w : expf(acc.w) - 1.f;
    }
    if (BF16OUT) {
        ushort4 o = {f2b(acc.x), f2b(acc.y), f2b(acc.z), f2b(acc.w)};
        *reinterpret_cast<ushort4*>(&outb[(long)d * CH + c]) = o;
    } else {
        *reinterpret_cast<float4*>(&outf[(long)d * CH + c]) = acc;
    }
}

// ---------------- launch ----------------

extern "C" void kernel_launch(void* const* d_in, const int* in_sizes, int n_in,
                              void* d_out, int out_size, void* d_ws, size_t ws_size,
                              hipStream_t stream) {
    const float* x0   = (const float*)d_in[0];
    const float* x1   = (const float*)d_in[1];
    const float* x2   = (const float*)d_in[2];
    const float* fcw0 = (const float*)d_in[3];
    const float* fcb0 = (const float*)d_in[4];
    const float* fcw1 = (const float*)d_in[5];
    const float* fcb1 = (const float*)d_in[6];
    const float* fcw2 = (const float*)d_in[7];
    const float* fcb2 = (const float*)d_in[8];
    const float* W0   = (const float*)d_in[9];
    const float* We0  = (const float*)d_in[10];
    const float* eemb0= (const float*)d_in[11];
    const float* al0  = (const float*)d_in[12];
    const float* ar0  = (const float*)d_in[13];
    const float* ae0  = (const float*)d_in[14];
    const float* W1   = (const float*)d_in[15];
    const float* We1  = (const float*)d_in[16];
    const float* eemb1= (const float*)d_in[17];
    const float* al1  = (const float*)d_in[18];
    const float* ar1  = (const float*)d_in[19];
    const float* ae1  = (const float*)d_in[20];
    const float* resW1= (const float*)d_in[21];
    const float* W2   = (const float*)d_in[22];
    const float* We2  = (const float*)d_in[23];
    const float* eemb2= (const float*)d_in[24];
    const float* al2  = (const float*)d_in[25];
    const float* ar2  = (const float*)d_in[26];
    const float* ae2  = (const float*)d_in[27];
    const float* resW2= (const float*)d_in[28];
    const int* src    = (const int*)d_in[29];
    const int* dst    = (const int*)d_in[30];
    const int* etype  = (const int*)d_in[31];

    const int n0 = in_sizes[0] / 128;
    const int n1 = in_sizes[1] / 256;
    const int n2 = in_sizes[2] / 64;
    const int N  = n0 + n1 + n2;
    const int E  = in_sizes[29];

    char* w = (char*)d_ws;
    auto alloc = [&](size_t bytes) {
        char* p = w;
        w += (bytes + 255) & ~(size_t)255;
        return p;
    };
    int*    counts  = (int*)alloc((size_t)N * 4);
    int*    offsets = (int*)alloc((size_t)(N + 1) * 4);
    int*    cursor  = (int*)alloc((size_t)N * 4);
    int*    src_s   = (int*)alloc((size_t)E * 4);
    int*    dst_s   = (int*)alloc((size_t)E * 4);
    int*    et_s    = (int*)alloc((size_t)E * 4);
    float*  e_csr   = (float*)alloc((size_t)E * 8 * 4);
    ushort* a0_csr  = (ushort*)alloc((size_t)E * 8 * 4);  // f32 a0 (layer0) -> reused as bf16 h2res
    ushort* h0bf    = (ushort*)alloc((size_t)N * 64 * 2);
    ushort* featb   = (ushort*)alloc((size_t)N * 256 * 2);
    ushort* h1bf    = (ushort*)alloc((size_t)N * 256 * 2);
    ushort* h2bf    = (ushort*)alloc((size_t)N * 256 * 2);
    float*  el      = (float*)alloc((size_t)N * 8 * 4);
    float*  er      = (float*)alloc((size_t)N * 8 * 4);
    float*  etatt   = (float*)alloc(6 * 8 * 4);
    ushort* Wt0     = (ushort*)alloc((size_t)256 * 64 * 2);
    ushort* Wt1     = (ushort*)alloc((size_t)256 * 256 * 2);
    ushort* WtR     = (ushort*)alloc((size_t)256 * 256 * 2);
    float*  feat2   = (float*)alloc((size_t)N * 16 * 4);
    float*  a0f     = (float*)a0_csr;   // f32 view for layer-0 attention save
    ushort* h2res   = a0_csr;           // bf16 view, reused AFTER layer-1 softmax consumed a0
    float*  out     = (float*)d_out;

    const int TB = 256;
    int eb = (E + TB - 1) / TB;

    // ---- CSR build ----
    hipMemsetAsync(counts, 0, (size_t)N * 4, stream);
    hist_kernel<<<eb, TB, 0, stream>>>(dst, counts, E);
    scan_kernel<<<1, 1024, 0, stream>>>(counts, offsets, N);
    hipMemcpyAsync(cursor, offsets, (size_t)N * 4, hipMemcpyDeviceToDevice, stream);
    scatter_kernel<<<eb, TB, 0, stream>>>(src, dst, etype, cursor, src_s, dst_s, et_s, E);

    // ---- weight prep ----
    wprep<<<(64 * 256 + TB - 1) / TB, TB, 0, stream>>>(W0, Wt0, 64, 256);
    wprep<<<(256 * 256 + TB - 1) / TB, TB, 0, stream>>>(W1, Wt1, 256, 256);
    wprep<<<(256 * 256 + TB - 1) / TB, TB, 0, stream>>>(resW1, WtR, 256, 256);

    // ---- input FC: h0bf = concat(x_i @ fcw_i + fcb_i) ----
    {
        dim3 g0(1, (n0 + 63) / 64);
        matmul64_fc<<<g0, TB, 0, stream>>>(x0, fcw0, fcb0, h0bf, n0, 128, 64);
        dim3 g1(1, (n1 + 63) / 64);
        matmul64_fc<<<g1, TB, 0, stream>>>(x1, fcw1, fcb1, h0bf + (long)n0 * 64, n1, 256, 64);
        dim3 g2(1, (n2 + 63) / 64);
        matmul64_fc<<<g2, TB, 0, stream>>>(x2, fcw2, fcb2, h0bf + (long)(n0 + n1) * 64, n2, 64, 64);
    }

    int nb_nh8 = (N * 8 + TB - 1) / TB;
    int nb_agg = (N * 64 + TB - 1) / TB;
    dim3 gg(256 / 128, (N + 127) / 128);

    // ---- layer 0 ----
    {
        gemm_bf16<false><<<gg, TB, 0, stream>>>(h0bf, Wt0, nullptr, featb, N, 256, 64);
        attn_lr_b<8, 32><<<nb_nh8, TB, 0, stream>>>(featb, al0, ar0, el, er, N);
        etype_att<8><<<6, 512, 0, stream>>>(eemb0, We0, ae0, etatt);
        edge_logits<8><<<eb, TB, 0, stream>>>(el, er, etatt, src_s, dst_s, et_s, e_csr, E);
        edge_softmax<8, false, true><<<nb_nh8, TB, 0, stream>>>(offsets, e_csr, nullptr, a0f, N);
        aggregate<8, 32, false, true, true, true><<<nb_agg, TB, 0, stream>>>(
            offsets, src_s, e_csr, nullptr, featb, nullptr, nullptr, h1bf, N);
    }

    // ---- layer 1 ----
    {
        gemm_bf16<false><<<gg, TB, 0, stream>>>(h1bf, Wt1, nullptr, featb, N, 256, 256);
        attn_lr_b<8, 32><<<nb_nh8, TB, 0, stream>>>(featb, al1, ar1, el, er, N);
        etype_att<8><<<6, 512, 0, stream>>>(eemb1, We1, ae1, etatt);
        edge_logits<8><<<eb, TB, 0, stream>>>(el, er, etatt, src_s, dst_s, et_s, e_csr, E);
        edge_softmax<8, true, false><<<nb_nh8, TB, 0, stream>>>(offsets, e_csr, a0f, nullptr, N);
        gemm_bf16<false><<<gg, TB, 0, stream>>>(h1bf, WtR, nullptr, h2res, N, 256, 256);
        aggregate<8, 32, true, true, true, true><<<nb_agg, TB, 0, stream>>>(
            offsets, src_s, e_csr, nullptr, featb, h2res, nullptr, h2bf, N);
    }

    // ---- layer 2 (H=1, OUT=16, residual, no activation) ----
    {
        matmul_n16b<false><<<(N + 15) / 16, TB, 0, stream>>>(h2bf, W2, feat2, N, 256);
        int nb_nh1 = (N + TB - 1) / TB;
        attn_lr<1, 16><<<nb_nh1, TB, 0, stream>>>(feat2, al2, ar2, el, er, N);
        etype_att<1><<<6, 64, 0, stream>>>(eemb2, We2, ae2, etatt);
        edge_logits<1><<<eb, TB, 0, stream>>>(el, er, etatt, src_s, dst_s, et_s, e_csr, E);
        edge_softmax<1, false, false><<<nb_nh1, TB, 0, stream>>>(offsets, e_csr, nullptr, nullptr, N);
        int nb_agg2 = (N * 4 + TB - 1) / TB;
        aggregate<1, 16, false, false, false, false><<<nb_agg2, TB, 0, stream>>>(
            offsets, src_s, e_csr, feat2, nullptr, nullptr, out, nullptr, N);
        matmul_n16b<true><<<(N + 15) / 16, TB, 0, stream>>>(h2bf, resW2, out, N, 256);
    }
}

// Round 5
// 525.531 us; speedup vs baseline: 2.5703x; 1.3414x over previous
//
#include <hip/hip_runtime.h>
#include <hip/hip_bf16.h>

#define ALPHA 0.05f
#define SLOPE 0.2f
#define LCAP 128

typedef __attribute__((ext_vector_type(8))) short short8v;
typedef __attribute__((ext_vector_type(8))) unsigned short ushort8v;
typedef __attribute__((ext_vector_type(4))) float floatx4;

__device__ inline ushort f2b(float f) {
    uint u = __float_as_uint(f);
    return (ushort)((u + 0x7fffu + ((u >> 16) & 1u)) >> 16);
}
__device__ inline float b2f(ushort b) { return __uint_as_float(((uint)b) << 16); }

// ---------------- CSR build ----------------

__global__ void hist_kernel(const int* __restrict__ dst, int* __restrict__ counts, int E) {
    int e = blockIdx.x * blockDim.x + threadIdx.x;
    if (e < E) atomicAdd(&counts[dst[e]], 1);
}

__global__ __launch_bounds__(256) void scan_part(const int* __restrict__ counts,
                                                 int* __restrict__ offsets,
                                                 int* __restrict__ partial, int n) {
    __shared__ int sd[256];
    int i = blockIdx.x * 256 + threadIdx.x;
    int v = (i < n) ? counts[i] : 0;
    sd[threadIdx.x] = v;
    __syncthreads();
    for (int off = 1; off < 256; off <<= 1) {
        int t = (threadIdx.x >= off) ? sd[threadIdx.x - off] : 0;
        __syncthreads();
        sd[threadIdx.x] += t;
        __syncthreads();
    }
    if (i < n) offsets[i + 1] = sd[threadIdx.x];
    if (threadIdx.x == 255) partial[blockIdx.x] = sd[255];
}

__global__ __launch_bounds__(256) void scan_top(int* __restrict__ partial, int nb) {
    __shared__ int sd[256];
    int v = (threadIdx.x < nb) ? partial[threadIdx.x] : 0;
    sd[threadIdx.x] = v;
    __syncthreads();
    for (int off = 1; off < 256; off <<= 1) {
        int t = (threadIdx.x >= off) ? sd[threadIdx.x - off] : 0;
        __syncthreads();
        sd[threadIdx.x] += t;
        __syncthreads();
    }
    if (threadIdx.x < nb) partial[threadIdx.x] = sd[threadIdx.x];
}

__global__ __launch_bounds__(256) void scan_add(int* __restrict__ offsets,
                                                const int* __restrict__ partial, int n) {
    int i = blockIdx.x * 256 + threadIdx.x;
    if (i == 0) offsets[0] = 0;
    if (blockIdx.x > 0 && i < n) offsets[i + 1] += partial[blockIdx.x - 1];
}

__global__ void scatter_kernel(const int* __restrict__ src, const int* __restrict__ dst,
                               const int* __restrict__ et, int* __restrict__ cursor,
                               int* __restrict__ src_s, int* __restrict__ dst_s,
                               int* __restrict__ et_s, int E) {
    int e = blockIdx.x * blockDim.x + threadIdx.x;
    if (e >= E) return;
    int d = dst[e];
    int pos = atomicAdd(&cursor[d], 1);
    src_s[pos] = src[e];
    dst_s[pos] = d;
    et_s[pos]  = et[e];
}

// ---------------- weight prep: W[K][N] f32 -> Wt[N][K] bf16 ----------------

__global__ void wprep(const float* __restrict__ W, ushort* __restrict__ Wt, int K, int N) {
    int i = blockIdx.x * blockDim.x + threadIdx.x;
    if (i >= K * N) return;
    int k = i / N, n = i % N;
    Wt[(long)n * K + k] = f2b(W[i]);
}

// ---------------- bf16 MFMA GEMM: C[M,N] = A[M,K] @ Bt[N,K]^T, bf16 out ----------------

__global__ __launch_bounds__(256) void gemm_bf16(const ushort* __restrict__ A,
                                                 const ushort* __restrict__ Bt,
                                                 ushort* __restrict__ Cb,
                                                 int M, int N, int K) {
    __shared__ ushort As[128][40];
    __shared__ ushort Bs[128][40];
    int bm = blockIdx.y * 128, bn = blockIdx.x * 128;
    int tid = threadIdx.x;
    int wave = tid >> 6, lane = tid & 63;
    int wm = (wave >> 1) * 64, wn = (wave & 1) * 64;
    floatx4 acc[4][4] = {};
    for (int k0 = 0; k0 < K; k0 += 32) {
#pragma unroll
        for (int it = 0; it < 2; ++it) {
            int idx = (tid + it * 256) * 8;
            int r = idx >> 5, c = idx & 31;
            int gr = bm + r;
            uint4 va = {0u, 0u, 0u, 0u};
            if (gr < M) va = *reinterpret_cast<const uint4*>(&A[(long)gr * K + k0 + c]);
            *reinterpret_cast<uint4*>(&As[r][c]) = va;
            uint4 vb = *reinterpret_cast<const uint4*>(&Bt[(long)(bn + r) * K + k0 + c]);
            *reinterpret_cast<uint4*>(&Bs[r][c]) = vb;
        }
        __syncthreads();
        int lr = lane & 15, lk = (lane >> 4) * 8;
        short8v af[4], bfr[4];
#pragma unroll
        for (int i = 0; i < 4; ++i)
            af[i] = *reinterpret_cast<const short8v*>(&As[wm + i * 16 + lr][lk]);
#pragma unroll
        for (int j = 0; j < 4; ++j)
            bfr[j] = *reinterpret_cast<const short8v*>(&Bs[wn + j * 16 + lr][lk]);
#pragma unroll
        for (int i = 0; i < 4; ++i)
#pragma unroll
            for (int j = 0; j < 4; ++j)
                acc[i][j] = __builtin_amdgcn_mfma_f32_16x16x32_bf16(af[i], bfr[j], acc[i][j], 0, 0, 0);
        __syncthreads();
    }
    int col = lane & 15, rbase = (lane >> 4) * 4;
#pragma unroll
    for (int i = 0; i < 4; ++i) {
#pragma unroll
        for (int r = 0; r < 4; ++r) {
            int gm = bm + wm + i * 16 + rbase + r;
            if (gm >= M) continue;
#pragma unroll
            for (int j = 0; j < 4; ++j) {
                int gn = bn + wn + j * 16 + col;
                Cb[(long)gm * N + gn] = f2b(acc[i][j][r]);
            }
        }
    }
}

// ---------------- input FC (f32 compute, bf16 out): C[M,64] = A@W + b ----------------

__global__ __launch_bounds__(256) void matmul64_fc(const float* __restrict__ A,
                                                   const float* __restrict__ W,
                                                   const float* __restrict__ bias,
                                                   ushort* __restrict__ C,
                                                   int M, int K, int N) {
    __shared__ float As[16][68];
    __shared__ float Bs[16][68];
    int bm = blockIdx.y * 64, bn = blockIdx.x * 64;
    int tx = threadIdx.x % 16, ty = threadIdx.x / 16;
    float acc[4][4] = {};
    for (int k0 = 0; k0 < K; k0 += 16) {
        for (int i = threadIdx.x; i < 64 * 16; i += 256) {
            int mm = i / 16, kk = i % 16;
            int gm = bm + mm;
            As[kk][mm] = (gm < M) ? A[(long)gm * K + k0 + kk] : 0.f;
        }
        for (int i = threadIdx.x; i < 16 * 64; i += 256) {
            int kk = i / 64, nn = i % 64;
            Bs[kk][nn] = W[(long)(k0 + kk) * N + bn + nn];
        }
        __syncthreads();
#pragma unroll
        for (int kk = 0; kk < 16; ++kk) {
            float a[4], b[4];
#pragma unroll
            for (int i = 0; i < 4; ++i) a[i] = As[kk][ty * 4 + i];
#pragma unroll
            for (int j = 0; j < 4; ++j) b[j] = Bs[kk][tx * 4 + j];
#pragma unroll
            for (int i = 0; i < 4; ++i)
#pragma unroll
                for (int j = 0; j < 4; ++j) acc[i][j] += a[i] * b[j];
        }
        __syncthreads();
    }
#pragma unroll
    for (int i = 0; i < 4; ++i) {
        int gm = bm + ty * 4 + i;
        if (gm >= M) continue;
#pragma unroll
        for (int j = 0; j < 4; ++j) {
            int gn = bn + tx * 4 + j;
            C[(long)gm * N + gn] = f2b(acc[i][j] + bias[gn]);
        }
    }
}

// ---------------- small N=16 matmul, bf16 A: C[M,16] = A[M,K] @ W[K,16] (+=) ----------------

template<bool ACC>
__global__ __launch_bounds__(256) void matmul_n16b(const ushort* __restrict__ A,
                                                   const float* __restrict__ W,
                                                   float* __restrict__ C, int M, int K) {
    __shared__ float Ws[256 * 16];
    for (int i = threadIdx.x; i < K * 16; i += 256) Ws[i] = W[i];
    __syncthreads();
    int m = blockIdx.x * 16 + threadIdx.x / 16;
    int nn = threadIdx.x % 16;
    if (m >= M) return;
    float s = 0.f;
    for (int k8 = 0; k8 < K / 8; ++k8) {
        uint4 v = *reinterpret_cast<const uint4*>(&A[(long)m * K + k8 * 8]);
        const uint* vp = reinterpret_cast<const uint*>(&v);
#pragma unroll
        for (int q = 0; q < 4; ++q) {
            uint w2 = vp[q];
            float f0 = __uint_as_float((w2 & 0xffffu) << 16);
            float f1 = __uint_as_float(w2 & 0xffff0000u);
            int k = k8 * 8 + q * 2;
            s += f0 * Ws[(k + 0) * 16 + nn] + f1 * Ws[(k + 1) * 16 + nn];
        }
    }
    if (ACC) s += C[(long)m * 16 + nn];
    C[(long)m * 16 + nn] = s;
}

// ---------------- attention pieces ----------------

// f32-feat version (layer 2)
template<int H, int OUT>
__global__ void attn_lr(const float* __restrict__ feat, const float* __restrict__ al,
                        const float* __restrict__ ar, float* __restrict__ el,
                        float* __restrict__ er, int N) {
    int gid = blockIdx.x * blockDim.x + threadIdx.x;
    int n = gid / H, h = gid % H;
    if (n >= N) return;
    const float* fr = feat + (long)n * H * OUT + h * OUT;
    float sl = 0.f, sr = 0.f;
#pragma unroll
    for (int o = 0; o < OUT; ++o) {
        float f = fr[o];
        sl += f * al[h * OUT + o];
        sr += f * ar[h * OUT + o];
    }
    el[n * H + h] = sl;
    er[n * H + h] = sr;
}

// bf16-feat version (layers 0/1)
template<int H, int OUT>
__global__ void attn_lr_b(const ushort* __restrict__ feat, const float* __restrict__ al,
                          const float* __restrict__ ar, float* __restrict__ el,
                          float* __restrict__ er, int N) {
    int gid = blockIdx.x * blockDim.x + threadIdx.x;
    int n = gid / H, h = gid % H;
    if (n >= N) return;
    const ushort* fr = feat + (long)n * H * OUT + h * OUT;
    float sl = 0.f, sr = 0.f;
#pragma unroll
    for (int q = 0; q < OUT / 8; ++q) {
        uint4 v = *reinterpret_cast<const uint4*>(&fr[q * 8]);
        const uint* vp = reinterpret_cast<const uint*>(&v);
#pragma unroll
        for (int i = 0; i < 4; ++i) {
            float f0 = __uint_as_float((vp[i] & 0xffffu) << 16);
            float f1 = __uint_as_float(vp[i] & 0xffff0000u);
            int o = q * 8 + i * 2;
            sl += f0 * al[h * OUT + o] + f1 * al[h * OUT + o + 1];
            sr += f0 * ar[h * OUT + o] + f1 * ar[h * OUT + o + 1];
        }
    }
    el[n * H + h] = sl;
    er[n * H + h] = sr;
}

// et_att[t,h] = sum_d (eemb[t] @ We)[h*64+d] * ae[h,d]
template<int H>
__global__ __launch_bounds__(H * 64) void etype_att(const float* __restrict__ eemb,
                                                    const float* __restrict__ We,
                                                    const float* __restrict__ ae,
                                                    float* __restrict__ out) {
    __shared__ float es[64];
    int t = blockIdx.x;
    int j = threadIdx.x;               // j = h*64 + d
    if (j < 64) es[j] = eemb[t * 64 + j];
    __syncthreads();
    float wsum = 0.f;
#pragma unroll 8
    for (int k = 0; k < 64; ++k) wsum += es[k] * We[k * (H * 64) + j];
    float v = wsum * ae[j];
#pragma unroll
    for (int off = 32; off > 0; off >>= 1) v += __shfl_down(v, off, 64);
    if ((j & 63) == 0) out[t * H + (j >> 6)] = v;
}

// ---------------- fused logits+softmax+aggregate, H=8, OUT=32, bf16 feat ----------------
// one block (64 threads) per dst node

template<bool BLEND, bool SAVE, bool RES>
__global__ __launch_bounds__(64) void fused_edge_h8(
    const int* __restrict__ offsets, const int* __restrict__ src_s,
    const int* __restrict__ et_s,
    const float* __restrict__ el, const float* __restrict__ er,
    const float* __restrict__ etatt,
    const ushort* __restrict__ featb,
    const float* __restrict__ a0_in, float* __restrict__ a0_out,
    const ushort* __restrict__ resin, ushort* __restrict__ outb, int N) {
    int d = blockIdx.x;
    int lane = threadIdx.x;
    int lo = offsets[d], hi = offsets[d + 1];
    int deg = hi - lo;
    __shared__ float a_lds[LCAP][8];
    __shared__ int   s_lds[LCAP];
    __shared__ float er_s[8];
    __shared__ float m_s[8], inv_s[8];
    if (lane < 8) er_s[lane] = er[d * 8 + lane];
    __syncthreads();
    bool fast = (deg <= LCAP);
    if (fast) {
        for (int i = lane; i < deg * 8; i += 64) {
            int p = i >> 3, h = i & 7;
            int s = src_s[lo + p], t = et_s[lo + p];
            if (h == 0) s_lds[p] = s;
            float v = el[s * 8 + h] + er_s[h] + etatt[t * 8 + h];
            a_lds[p][h] = v > 0.f ? v : SLOPE * v;
        }
        __syncthreads();
        if (lane < 8) {
            int h = lane;
            float m = -INFINITY;
            for (int p = 0; p < deg; ++p) m = fmaxf(m, a_lds[p][h]);
            float ssum = 0.f;
            for (int p = 0; p < deg; ++p) ssum += expf(a_lds[p][h] - m);
            m_s[h] = m;
            inv_s[h] = ssum > 0.f ? 1.f / ssum : 0.f;
        }
        __syncthreads();
        for (int i = lane; i < deg * 8; i += 64) {
            int p = i >> 3, h = i & 7;
            float a = expf(a_lds[p][h] - m_s[h]) * inv_s[h];
            if (BLEND) a = a * (1.f - ALPHA) + a0_in[lo * 8 + i] * ALPHA;
            a_lds[p][h] = a;
            if (SAVE) a0_out[lo * 8 + i] = a;
        }
        __syncthreads();
    } else {
        // fallback: recompute logits (rare; any degree)
        if (lane < 8) {
            int h = lane;
            float m = -INFINITY;
            for (int p = 0; p < deg; ++p) {
                int s = src_s[lo + p], t = et_s[lo + p];
                float v = el[s * 8 + h] + er_s[h] + etatt[t * 8 + h];
                v = v > 0.f ? v : SLOPE * v;
                m = fmaxf(m, v);
            }
            float ssum = 0.f;
            for (int p = 0; p < deg; ++p) {
                int s = src_s[lo + p], t = et_s[lo + p];
                float v = el[s * 8 + h] + er_s[h] + etatt[t * 8 + h];
                v = v > 0.f ? v : SLOPE * v;
                ssum += expf(v - m);
            }
            m_s[h] = m;
            inv_s[h] = ssum > 0.f ? 1.f / ssum : 0.f;
        }
        __syncthreads();
        if (SAVE) {
            for (int i = lane; i < deg * 8; i += 64) {
                int p = i >> 3, h = i & 7;
                int s = src_s[lo + p], t = et_s[lo + p];
                float v = el[s * 8 + h] + er_s[h] + etatt[t * 8 + h];
                v = v > 0.f ? v : SLOPE * v;
                float a = expf(v - m_s[h]) * inv_s[h];
                if (BLEND) a = a * (1.f - ALPHA) + a0_in[lo * 8 + i] * ALPHA;
                a0_out[lo * 8 + i] = a;
            }
        }
    }
    // aggregation: 2 edges in flight (half-wave each), 16B loads
    int half = lane >> 5, t = lane & 31;
    float acc[8];
#pragma unroll
    for (int k = 0; k < 8; ++k) acc[k] = 0.f;
    if (RES && half == 0) {
        ushort8v r = *reinterpret_cast<const ushort8v*>(&resin[(long)d * 256 + t * 8]);
#pragma unroll
        for (int k = 0; k < 8; ++k) acc[k] = b2f((ushort)r[k]);
    }
    int h = t >> 2;
    for (int p = half; p < deg; p += 2) {
        int s;
        float a;
        if (fast) {
            s = s_lds[p];
            a = a_lds[p][h];
        } else {
            s = src_s[lo + p];
            int tt = et_s[lo + p];
            float v = el[s * 8 + h] + er_s[h] + etatt[tt * 8 + h];
            v = v > 0.f ? v : SLOPE * v;
            a = expf(v - m_s[h]) * inv_s[h];
            if (BLEND) a = a * (1.f - ALPHA) + a0_in[(long)(lo + p) * 8 + h] * ALPHA;
        }
        ushort8v f = *reinterpret_cast<const ushort8v*>(&featb[(long)s * 256 + t * 8]);
#pragma unroll
        for (int k = 0; k < 8; ++k) acc[k] += b2f((ushort)f[k]) * a;
    }
#pragma unroll
    for (int k = 0; k < 8; ++k) acc[k] += __shfl_down(acc[k], 32);
    if (half == 0) {
        ushort8v o;
#pragma unroll
        for (int k = 0; k < 8; ++k) {
            float v = acc[k];
            v = v > 0.f ? v : expf(v) - 1.f;
            o[k] = f2b(v);
        }
        *reinterpret_cast<ushort8v*>(&outb[(long)d * 256 + t * 8]) = o;
    }
}

// ---------------- fused edge kernel, H=1, OUT=16, f32 feat, no ELU ----------------

__global__ __launch_bounds__(64) void fused_edge_h1(
    const int* __restrict__ offsets, const int* __restrict__ src_s,
    const int* __restrict__ et_s,
    const float* __restrict__ el, const float* __restrict__ er,
    const float* __restrict__ etatt,
    const float* __restrict__ feat, float* __restrict__ out, int N) {
    int d = blockIdx.x;
    int lane = threadIdx.x;
    int lo = offsets[d], hi = offsets[d + 1];
    int deg = hi - lo;
    __shared__ float a_lds[512];
    __shared__ float stats[2];
    float er_d = er[d];
    bool fast = (deg <= 512);
    if (fast) {
        for (int i = lane; i < deg; i += 64) {
            int s = src_s[lo + i], t = et_s[lo + i];
            float v = el[s] + er_d + etatt[t];
            a_lds[i] = v > 0.f ? v : SLOPE * v;
        }
        __syncthreads();
        if (lane == 0) {
            float m = -INFINITY;
            for (int i = 0; i < deg; ++i) m = fmaxf(m, a_lds[i]);
            float ssum = 0.f;
            for (int i = 0; i < deg; ++i) ssum += expf(a_lds[i] - m);
            stats[0] = m;
            stats[1] = ssum > 0.f ? 1.f / ssum : 0.f;
        }
        __syncthreads();
        for (int i = lane; i < deg; i += 64) a_lds[i] = expf(a_lds[i] - stats[0]) * stats[1];
        __syncthreads();
    } else {
        if (lane == 0) {
            float m = -INFINITY;
            for (int i = 0; i < deg; ++i) {
                int s = src_s[lo + i], t = et_s[lo + i];
                float v = el[s] + er_d + etatt[t];
                v = v > 0.f ? v : SLOPE * v;
                m = fmaxf(m, v);
            }
            float ssum = 0.f;
            for (int i = 0; i < deg; ++i) {
                int s = src_s[lo + i], t = et_s[lo + i];
                float v = el[s] + er_d + etatt[t];
                v = v > 0.f ? v : SLOPE * v;
                ssum += expf(v - m);
            }
            stats[0] = m;
            stats[1] = ssum > 0.f ? 1.f / ssum : 0.f;
        }
        __syncthreads();
    }
    int g = lane >> 2, t = lane & 3;
    float4 acc = {0.f, 0.f, 0.f, 0.f};
    for (int p = g; p < deg; p += 16) {
        int s = src_s[lo + p];
        float a;
        if (fast) a = a_lds[p];
        else {
            int tt = et_s[lo + p];
            float v = el[s] + er_d + etatt[tt];
            v = v > 0.f ? v : SLOPE * v;
            a = expf(v - stats[0]) * stats[1];
        }
        float4 f = *reinterpret_cast<const float4*>(&feat[(long)s * 16 + t * 4]);
        acc.x += f.x * a;
        acc.y += f.y * a;
        acc.z += f.z * a;
        acc.w += f.w * a;
    }
#pragma unroll
    for (int off = 4; off < 64; off <<= 1) {
        acc.x += __shfl_down(acc.x, off);
        acc.y += __shfl_down(acc.y, off);
        acc.z += __shfl_down(acc.z, off);
        acc.w += __shfl_down(acc.w, off);
    }
    if (lane < 4) *reinterpret_cast<float4*>(&out[(long)d * 16 + t * 4]) = acc;
}

// ---------------- launch ----------------

extern "C" void kernel_launch(void* const* d_in, const int* in_sizes, int n_in,
                              void* d_out, int out_size, void* d_ws, size_t ws_size,
                              hipStream_t stream) {
    const float* x0   = (const float*)d_in[0];
    const float* x1   = (const float*)d_in[1];
    const float* x2   = (const float*)d_in[2];
    const float* fcw0 = (const float*)d_in[3];
    const float* fcb0 = (const float*)d_in[4];
    const float* fcw1 = (const float*)d_in[5];
    const float* fcb1 = (const float*)d_in[6];
    const float* fcw2 = (const float*)d_in[7];
    const float* fcb2 = (const float*)d_in[8];
    const float* W0   = (const float*)d_in[9];
    const float* We0  = (const float*)d_in[10];
    const float* eemb0= (const float*)d_in[11];
    const float* al0  = (const float*)d_in[12];
    const float* ar0  = (const float*)d_in[13];
    const float* ae0  = (const float*)d_in[14];
    const float* W1   = (const float*)d_in[15];
    const float* We1  = (const float*)d_in[16];
    const float* eemb1= (const float*)d_in[17];
    const float* al1  = (const float*)d_in[18];
    const float* ar1  = (const float*)d_in[19];
    const float* ae1  = (const float*)d_in[20];
    const float* resW1= (const float*)d_in[21];
    const float* W2   = (const float*)d_in[22];
    const float* We2  = (const float*)d_in[23];
    const float* eemb2= (const float*)d_in[24];
    const float* al2  = (const float*)d_in[25];
    const float* ar2  = (const float*)d_in[26];
    const float* ae2  = (const float*)d_in[27];
    const float* resW2= (const float*)d_in[28];
    const int* src    = (const int*)d_in[29];
    const int* dst    = (const int*)d_in[30];
    const int* etype  = (const int*)d_in[31];

    const int n0 = in_sizes[0] / 128;
    const int n1 = in_sizes[1] / 256;
    const int n2 = in_sizes[2] / 64;
    const int N  = n0 + n1 + n2;
    const int E  = in_sizes[29];

    char* w = (char*)d_ws;
    auto alloc = [&](size_t bytes) {
        char* p = w;
        w += (bytes + 255) & ~(size_t)255;
        return p;
    };
    int*    counts  = (int*)alloc((size_t)N * 4);
    int*    offsets = (int*)alloc((size_t)(N + 1) * 4);
    int*    cursor  = (int*)alloc((size_t)N * 4);
    int*    partial = (int*)alloc(1024 * 4);
    int*    src_s   = (int*)alloc((size_t)E * 4);
    int*    dst_s   = (int*)alloc((size_t)E * 4);
    int*    et_s    = (int*)alloc((size_t)E * 4);
    ushort* h2res   = (ushort*)alloc((size_t)N * 256 * 2);
    float*  a0f     = (float*)alloc((size_t)E * 8 * 4);
    ushort* h0bf    = (ushort*)alloc((size_t)N * 64 * 2);
    ushort* featb   = (ushort*)alloc((size_t)N * 256 * 2);
    ushort* h1bf    = (ushort*)alloc((size_t)N * 256 * 2);
    ushort* h2bf    = (ushort*)alloc((size_t)N * 256 * 2);
    float*  el      = (float*)alloc((size_t)N * 8 * 4);
    float*  er      = (float*)alloc((size_t)N * 8 * 4);
    float*  etatt   = (float*)alloc(6 * 8 * 4);
    ushort* Wt0     = (ushort*)alloc((size_t)256 * 64 * 2);
    ushort* Wt1     = (ushort*)alloc((size_t)256 * 256 * 2);
    ushort* WtR     = (ushort*)alloc((size_t)256 * 256 * 2);
    float*  feat2   = (float*)alloc((size_t)N * 16 * 4);
    float*  out     = (float*)d_out;

    const int TB = 256;
    int eb = (E + TB - 1) / TB;
    int nb1 = (N + 255) / 256;

    // ---- CSR build ----
    hipMemsetAsync(counts, 0, (size_t)N * 4, stream);
    hist_kernel<<<eb, TB, 0, stream>>>(dst, counts, E);
    scan_part<<<nb1, 256, 0, stream>>>(counts, offsets, partial, N);
    scan_top<<<1, 256, 0, stream>>>(partial, nb1);
    scan_add<<<nb1, 256, 0, stream>>>(offsets, partial, N);
    hipMemcpyAsync(cursor, offsets, (size_t)N * 4, hipMemcpyDeviceToDevice, stream);
    scatter_kernel<<<eb, TB, 0, stream>>>(src, dst, etype, cursor, src_s, dst_s, et_s, E);

    // ---- weight prep ----
    wprep<<<(64 * 256 + TB - 1) / TB, TB, 0, stream>>>(W0, Wt0, 64, 256);
    wprep<<<(256 * 256 + TB - 1) / TB, TB, 0, stream>>>(W1, Wt1, 256, 256);
    wprep<<<(256 * 256 + TB - 1) / TB, TB, 0, stream>>>(resW1, WtR, 256, 256);

    // ---- input FC: h0bf = concat(x_i @ fcw_i + fcb_i) ----
    {
        dim3 g0(1, (n0 + 63) / 64);
        matmul64_fc<<<g0, TB, 0, stream>>>(x0, fcw0, fcb0, h0bf, n0, 128, 64);
        dim3 g1(1, (n1 + 63) / 64);
        matmul64_fc<<<g1, TB, 0, stream>>>(x1, fcw1, fcb1, h0bf + (long)n0 * 64, n1, 256, 64);
        dim3 g2(1, (n2 + 63) / 64);
        matmul64_fc<<<g2, TB, 0, stream>>>(x2, fcw2, fcb2, h0bf + (long)(n0 + n1) * 64, n2, 64, 64);
    }

    int nb_nh8 = (N * 8 + TB - 1) / TB;
    dim3 gg(256 / 128, (N + 127) / 128);

    // ---- layer 0 ----
    {
        gemm_bf16<<<gg, TB, 0, stream>>>(h0bf, Wt0, featb, N, 256, 64);
        attn_lr_b<8, 32><<<nb_nh8, TB, 0, stream>>>(featb, al0, ar0, el, er, N);
        etype_att<8><<<6, 512, 0, stream>>>(eemb0, We0, ae0, etatt);
        fused_edge_h8<false, true, false><<<N, 64, 0, stream>>>(
            offsets, src_s, et_s, el, er, etatt, featb, nullptr, a0f, nullptr, h1bf, N);
    }

    // ---- layer 1 ----
    {
        gemm_bf16<<<gg, TB, 0, stream>>>(h1bf, Wt1, featb, N, 256, 256);
        attn_lr_b<8, 32><<<nb_nh8, TB, 0, stream>>>(featb, al1, ar1, el, er, N);
        etype_att<8><<<6, 512, 0, stream>>>(eemb1, We1, ae1, etatt);
        gemm_bf16<<<gg, TB, 0, stream>>>(h1bf, WtR, h2res, N, 256, 256);
        fused_edge_h8<true, false, true><<<N, 64, 0, stream>>>(
            offsets, src_s, et_s, el, er, etatt, featb, a0f, nullptr, h2res, h2bf, N);
    }

    // ---- layer 2 (H=1, OUT=16, residual, no activation) ----
    {
        matmul_n16b<false><<<(N + 15) / 16, TB, 0, stream>>>(h2bf, W2, feat2, N, 256);
        int nb_nh1 = (N + TB - 1) / TB;
        attn_lr<1, 16><<<nb_nh1, TB, 0, stream>>>(feat2, al2, ar2, el, er, N);
        etype_att<1><<<6, 64, 0, stream>>>(eemb2, We2, ae2, etatt);
        fused_edge_h1<<<N, 64, 0, stream>>>(offsets, src_s, et_s, el, er, etatt, feat2, out, N);
        matmul_n16b<true><<<(N + 15) / 16, TB, 0, stream>>>(h2bf, resW2, out, N, 256);
    }
}

// Round 6
// 510.533 us; speedup vs baseline: 2.6458x; 1.0294x over previous
//
#include <hip/hip_runtime.h>
#include <hip/hip_bf16.h>

#define ALPHA 0.05f
#define SLOPE 0.2f
#define LCAP 128

typedef __attribute__((ext_vector_type(8))) short short8v;
typedef __attribute__((ext_vector_type(8))) unsigned short ushort8v;
typedef __attribute__((ext_vector_type(4))) float floatx4;

__device__ inline ushort f2b(float f) {
    uint u = __float_as_uint(f);
    return (ushort)((u + 0x7fffu + ((u >> 16) & 1u)) >> 16);
}
__device__ inline float b2f(ushort b) { return __uint_as_float(((uint)b) << 16); }

// ---------------- CSR build ----------------

__global__ void hist_kernel(const int* __restrict__ dst, int* __restrict__ counts, int E) {
    int e = blockIdx.x * blockDim.x + threadIdx.x;
    if (e < E) atomicAdd(&counts[dst[e]], 1);
}

__global__ __launch_bounds__(256) void scan_part(const int* __restrict__ counts,
                                                 int* __restrict__ offsets,
                                                 int* __restrict__ partial, int n) {
    __shared__ int sd[256];
    int i = blockIdx.x * 256 + threadIdx.x;
    int v = (i < n) ? counts[i] : 0;
    sd[threadIdx.x] = v;
    __syncthreads();
    for (int off = 1; off < 256; off <<= 1) {
        int t = (threadIdx.x >= off) ? sd[threadIdx.x - off] : 0;
        __syncthreads();
        sd[threadIdx.x] += t;
        __syncthreads();
    }
    if (i < n) offsets[i + 1] = sd[threadIdx.x];
    if (threadIdx.x == 255) partial[blockIdx.x] = sd[255];
}

__global__ __launch_bounds__(256) void scan_top(int* __restrict__ partial, int nb) {
    __shared__ int sd[256];
    int v = (threadIdx.x < nb) ? partial[threadIdx.x] : 0;
    sd[threadIdx.x] = v;
    __syncthreads();
    for (int off = 1; off < 256; off <<= 1) {
        int t = (threadIdx.x >= off) ? sd[threadIdx.x - off] : 0;
        __syncthreads();
        sd[threadIdx.x] += t;
        __syncthreads();
    }
    if (threadIdx.x < nb) partial[threadIdx.x] = sd[threadIdx.x];
}

__global__ __launch_bounds__(256) void scan_add(int* __restrict__ offsets,
                                                const int* __restrict__ partial, int n) {
    int i = blockIdx.x * 256 + threadIdx.x;
    if (i == 0) offsets[0] = 0;
    if (blockIdx.x > 0 && i < n) offsets[i + 1] += partial[blockIdx.x - 1];
}

__global__ void scatter_kernel(const int* __restrict__ src, const int* __restrict__ dst,
                               const int* __restrict__ et, int* __restrict__ cursor,
                               int* __restrict__ src_s, int* __restrict__ et_s, int E) {
    int e = blockIdx.x * blockDim.x + threadIdx.x;
    if (e >= E) return;
    int d = dst[e];
    int pos = atomicAdd(&cursor[d], 1);
    src_s[pos] = src[e];
    et_s[pos]  = et[e];
}

// ---------------- weight prep: W[K][N] f32 -> Wt[N][K] bf16 ----------------

__global__ void wprep(const float* __restrict__ W, ushort* __restrict__ Wt, int K, int N) {
    int i = blockIdx.x * blockDim.x + threadIdx.x;
    if (i >= K * N) return;
    int k = i / N, n = i % N;
    Wt[(long)n * K + k] = f2b(W[i]);
}

// ---------------- bf16 MFMA GEMM: C[M,N] = A[M,K] @ Bt[N,K]^T, bf16 out ----------------

__global__ __launch_bounds__(256) void gemm_bf16(const ushort* __restrict__ A,
                                                 const ushort* __restrict__ Bt,
                                                 ushort* __restrict__ Cb,
                                                 int M, int N, int K) {
    __shared__ ushort As[128][40];
    __shared__ ushort Bs[128][40];
    int bm = blockIdx.y * 128, bn = blockIdx.x * 128;
    int tid = threadIdx.x;
    int wave = tid >> 6, lane = tid & 63;
    int wm = (wave >> 1) * 64, wn = (wave & 1) * 64;
    floatx4 acc[4][4] = {};
    for (int k0 = 0; k0 < K; k0 += 32) {
#pragma unroll
        for (int it = 0; it < 2; ++it) {
            int idx = (tid + it * 256) * 8;
            int r = idx >> 5, c = idx & 31;
            int gr = bm + r;
            uint4 va = {0u, 0u, 0u, 0u};
            if (gr < M) va = *reinterpret_cast<const uint4*>(&A[(long)gr * K + k0 + c]);
            *reinterpret_cast<uint4*>(&As[r][c]) = va;
            uint4 vb = *reinterpret_cast<const uint4*>(&Bt[(long)(bn + r) * K + k0 + c]);
            *reinterpret_cast<uint4*>(&Bs[r][c]) = vb;
        }
        __syncthreads();
        int lr = lane & 15, lk = (lane >> 4) * 8;
        short8v af[4], bfr[4];
#pragma unroll
        for (int i = 0; i < 4; ++i)
            af[i] = *reinterpret_cast<const short8v*>(&As[wm + i * 16 + lr][lk]);
#pragma unroll
        for (int j = 0; j < 4; ++j)
            bfr[j] = *reinterpret_cast<const short8v*>(&Bs[wn + j * 16 + lr][lk]);
#pragma unroll
        for (int i = 0; i < 4; ++i)
#pragma unroll
            for (int j = 0; j < 4; ++j)
                acc[i][j] = __builtin_amdgcn_mfma_f32_16x16x32_bf16(af[i], bfr[j], acc[i][j], 0, 0, 0);
        __syncthreads();
    }
    int col = lane & 15, rbase = (lane >> 4) * 4;
#pragma unroll
    for (int i = 0; i < 4; ++i) {
#pragma unroll
        for (int r = 0; r < 4; ++r) {
            int gm = bm + wm + i * 16 + rbase + r;
            if (gm >= M) continue;
#pragma unroll
            for (int j = 0; j < 4; ++j) {
                int gn = bn + wn + j * 16 + col;
                Cb[(long)gm * N + gn] = f2b(acc[i][j][r]);
            }
        }
    }
}

// ---------------- input FC (f32 compute, bf16 out): C[M,64] = A@W + b ----------------

__global__ __launch_bounds__(256) void matmul64_fc(const float* __restrict__ A,
                                                   const float* __restrict__ W,
                                                   const float* __restrict__ bias,
                                                   ushort* __restrict__ C,
                                                   int M, int K, int N) {
    __shared__ float As[16][68];
    __shared__ float Bs[16][68];
    int bm = blockIdx.y * 64, bn = blockIdx.x * 64;
    int tx = threadIdx.x % 16, ty = threadIdx.x / 16;
    float acc[4][4] = {};
    for (int k0 = 0; k0 < K; k0 += 16) {
        for (int i = threadIdx.x; i < 64 * 16; i += 256) {
            int mm = i / 16, kk = i % 16;
            int gm = bm + mm;
            As[kk][mm] = (gm < M) ? A[(long)gm * K + k0 + kk] : 0.f;
        }
        for (int i = threadIdx.x; i < 16 * 64; i += 256) {
            int kk = i / 64, nn = i % 64;
            Bs[kk][nn] = W[(long)(k0 + kk) * N + bn + nn];
        }
        __syncthreads();
#pragma unroll
        for (int kk = 0; kk < 16; ++kk) {
            float a[4], b[4];
#pragma unroll
            for (int i = 0; i < 4; ++i) a[i] = As[kk][ty * 4 + i];
#pragma unroll
            for (int j = 0; j < 4; ++j) b[j] = Bs[kk][tx * 4 + j];
#pragma unroll
            for (int i = 0; i < 4; ++i)
#pragma unroll
                for (int j = 0; j < 4; ++j) acc[i][j] += a[i] * b[j];
        }
        __syncthreads();
    }
#pragma unroll
    for (int i = 0; i < 4; ++i) {
        int gm = bm + ty * 4 + i;
        if (gm >= M) continue;
#pragma unroll
        for (int j = 0; j < 4; ++j) {
            int gn = bn + tx * 4 + j;
            C[(long)gm * N + gn] = f2b(acc[i][j] + bias[gn]);
        }
    }
}

// ---------------- small N=16 matmul, bf16 A: C[M,16] = A[M,K] @ W[K,16] (+=) ----------------

template<bool ACC>
__global__ __launch_bounds__(256) void matmul_n16b(const ushort* __restrict__ A,
                                                   const float* __restrict__ W,
                                                   float* __restrict__ C, int M, int K) {
    __shared__ float Ws[256 * 16];
    for (int i = threadIdx.x; i < K * 16; i += 256) Ws[i] = W[i];
    __syncthreads();
    int m = blockIdx.x * 16 + threadIdx.x / 16;
    int nn = threadIdx.x % 16;
    if (m >= M) return;
    float s = 0.f;
    for (int k8 = 0; k8 < K / 8; ++k8) {
        uint4 v = *reinterpret_cast<const uint4*>(&A[(long)m * K + k8 * 8]);
        const uint* vp = reinterpret_cast<const uint*>(&v);
#pragma unroll
        for (int q = 0; q < 4; ++q) {
            uint w2 = vp[q];
            float f0 = __uint_as_float((w2 & 0xffffu) << 16);
            float f1 = __uint_as_float(w2 & 0xffff0000u);
            int k = k8 * 8 + q * 2;
            s += f0 * Ws[(k + 0) * 16 + nn] + f1 * Ws[(k + 1) * 16 + nn];
        }
    }
    if (ACC) s += C[(long)m * 16 + nn];
    C[(long)m * 16 + nn] = s;
}

// ---------------- attention pieces ----------------

// f32-feat version (layer 2)
template<int H, int OUT>
__global__ void attn_lr(const float* __restrict__ feat, const float* __restrict__ al,
                        const float* __restrict__ ar, float* __restrict__ el,
                        float* __restrict__ er, int N) {
    int gid = blockIdx.x * blockDim.x + threadIdx.x;
    int n = gid / H, h = gid % H;
    if (n >= N) return;
    const float* fr = feat + (long)n * H * OUT + h * OUT;
    float sl = 0.f, sr = 0.f;
#pragma unroll
    for (int o = 0; o < OUT; ++o) {
        float f = fr[o];
        sl += f * al[h * OUT + o];
        sr += f * ar[h * OUT + o];
    }
    el[n * H + h] = sl;
    er[n * H + h] = sr;
}

// bf16-feat version (layers 0/1)
template<int H, int OUT>
__global__ void attn_lr_b(const ushort* __restrict__ feat, const float* __restrict__ al,
                          const float* __restrict__ ar, float* __restrict__ el,
                          float* __restrict__ er, int N) {
    int gid = blockIdx.x * blockDim.x + threadIdx.x;
    int n = gid / H, h = gid % H;
    if (n >= N) return;
    const ushort* fr = feat + (long)n * H * OUT + h * OUT;
    float sl = 0.f, sr = 0.f;
#pragma unroll
    for (int q = 0; q < OUT / 8; ++q) {
        uint4 v = *reinterpret_cast<const uint4*>(&fr[q * 8]);
        const uint* vp = reinterpret_cast<const uint*>(&v);
#pragma unroll
        for (int i = 0; i < 4; ++i) {
            float f0 = __uint_as_float((vp[i] & 0xffffu) << 16);
            float f1 = __uint_as_float(vp[i] & 0xffff0000u);
            int o = q * 8 + i * 2;
            sl += f0 * al[h * OUT + o] + f1 * al[h * OUT + o + 1];
            sr += f0 * ar[h * OUT + o] + f1 * ar[h * OUT + o + 1];
        }
    }
    el[n * H + h] = sl;
    er[n * H + h] = sr;
}

// et_att[t,h] = sum_d (eemb[t] @ We)[h*64+d] * ae[h,d]
template<int H>
__global__ __launch_bounds__(H * 64) void etype_att(const float* __restrict__ eemb,
                                                    const float* __restrict__ We,
                                                    const float* __restrict__ ae,
                                                    float* __restrict__ out) {
    __shared__ float es[64];
    int t = blockIdx.x;
    int j = threadIdx.x;               // j = h*64 + d
    if (j < 64) es[j] = eemb[t * 64 + j];
    __syncthreads();
    float wsum = 0.f;
#pragma unroll 8
    for (int k = 0; k < 64; ++k) wsum += es[k] * We[k * (H * 64) + j];
    float v = wsum * ae[j];
#pragma unroll
    for (int off = 32; off > 0; off >>= 1) v += __shfl_down(v, off, 64);
    if ((j & 63) == 0) out[t * H + (j >> 6)] = v;
}

// ---------------- fused logits+softmax+aggregate, H=8, OUT=32, bf16 feat ----------------
// one block (64 threads = 1 wave) per dst node

template<bool BLEND, bool SAVE, bool RES>
__global__ __launch_bounds__(64) void fused_edge_h8(
    const int* __restrict__ offsets, const int* __restrict__ src_s,
    const int* __restrict__ et_s,
    const float* __restrict__ el, const float* __restrict__ er,
    const float* __restrict__ etatt,
    const ushort* __restrict__ featb,
    const float* __restrict__ a0_in, float* __restrict__ a0_out,
    const ushort* __restrict__ resin, ushort* __restrict__ outb, int N) {
    int d = blockIdx.x;
    int lane = threadIdx.x;
    int lo = offsets[d], hi = offsets[d + 1];
    int deg = hi - lo;
    __shared__ float a_lds[LCAP][8];
    __shared__ int   s_lds[LCAP];
    __shared__ float er_s[8];
    __shared__ float m_s[8], inv_s[8];
    if (lane < 8) er_s[lane] = er[d * 8 + lane];
    __syncthreads();
    bool fast = (deg <= LCAP);
    if (fast) {
        for (int i = lane; i < deg * 8; i += 64) {
            int p = i >> 3, h = i & 7;
            int s = src_s[lo + p], t = et_s[lo + p];
            if (h == 0) s_lds[p] = s;
            float v = el[s * 8 + h] + er_s[h] + etatt[t * 8 + h];
            a_lds[p][h] = v > 0.f ? v : SLOPE * v;
        }
        __syncthreads();
        {
            // wave-parallel softmax stats: lane = g*8 + h
            int g = lane >> 3, h = lane & 7;
            float m = -INFINITY;
            for (int p = g; p < deg; p += 8) m = fmaxf(m, a_lds[p][h]);
#pragma unroll
            for (int off = 8; off < 64; off <<= 1) m = fmaxf(m, __shfl_xor(m, off, 64));
            float ssum = 0.f;
            for (int p = g; p < deg; p += 8) ssum += __expf(a_lds[p][h] - m);
#pragma unroll
            for (int off = 8; off < 64; off <<= 1) ssum += __shfl_xor(ssum, off, 64);
            if (g == 0) {
                m_s[h] = m;
                inv_s[h] = ssum > 0.f ? 1.f / ssum : 0.f;
            }
        }
        __syncthreads();
        for (int i = lane; i < deg * 8; i += 64) {
            int p = i >> 3, h = i & 7;
            float a = __expf(a_lds[p][h] - m_s[h]) * inv_s[h];
            if (BLEND) a = a * (1.f - ALPHA) + a0_in[lo * 8 + i] * ALPHA;
            a_lds[p][h] = a;
            if (SAVE) a0_out[lo * 8 + i] = a;
        }
        __syncthreads();
    } else {
        // fallback: recompute logits (rare; any degree)
        int g = lane >> 3, h = lane & 7;
        float m = -INFINITY;
        for (int p = g; p < deg; p += 8) {
            int s = src_s[lo + p], t = et_s[lo + p];
            float v = el[s * 8 + h] + er_s[h] + etatt[t * 8 + h];
            v = v > 0.f ? v : SLOPE * v;
            m = fmaxf(m, v);
        }
#pragma unroll
        for (int off = 8; off < 64; off <<= 1) m = fmaxf(m, __shfl_xor(m, off, 64));
        float ssum = 0.f;
        for (int p = g; p < deg; p += 8) {
            int s = src_s[lo + p], t = et_s[lo + p];
            float v = el[s * 8 + h] + er_s[h] + etatt[t * 8 + h];
            v = v > 0.f ? v : SLOPE * v;
            ssum += __expf(v - m);
        }
#pragma unroll
        for (int off = 8; off < 64; off <<= 1) ssum += __shfl_xor(ssum, off, 64);
        if (g == 0) {
            m_s[h] = m;
            inv_s[h] = ssum > 0.f ? 1.f / ssum : 0.f;
        }
        __syncthreads();
        if (SAVE) {
            for (int i = lane; i < deg * 8; i += 64) {
                int p = i >> 3, hh = i & 7;
                int s = src_s[lo + p], t = et_s[lo + p];
                float v = el[s * 8 + hh] + er_s[hh] + etatt[t * 8 + hh];
                v = v > 0.f ? v : SLOPE * v;
                float a = __expf(v - m_s[hh]) * inv_s[hh];
                if (BLEND) a = a * (1.f - ALPHA) + a0_in[lo * 8 + i] * ALPHA;
                a0_out[lo * 8 + i] = a;
            }
        }
    }
    // aggregation: 2 edges in flight (half-wave each), 16B loads, uint-pair unpack
    int half = lane >> 5, t = lane & 31;
    float acc[8];
#pragma unroll
    for (int k = 0; k < 8; ++k) acc[k] = 0.f;
    if (RES && half == 0) {
        uint4 rv = *reinterpret_cast<const uint4*>(&resin[(long)d * 256 + t * 8]);
        const uint* rp = reinterpret_cast<const uint*>(&rv);
#pragma unroll
        for (int q = 0; q < 4; ++q) {
            acc[2 * q]     = __uint_as_float(rp[q] << 16);
            acc[2 * q + 1] = __uint_as_float(rp[q] & 0xffff0000u);
        }
    }
    int h = t >> 2;
    for (int p = half; p < deg; p += 2) {
        int s;
        float a;
        if (fast) {
            s = s_lds[p];
            a = a_lds[p][h];
        } else {
            s = src_s[lo + p];
            int tt = et_s[lo + p];
            float v = el[s * 8 + h] + er_s[h] + etatt[tt * 8 + h];
            v = v > 0.f ? v : SLOPE * v;
            a = __expf(v - m_s[h]) * inv_s[h];
            if (BLEND) a = a * (1.f - ALPHA) + a0_in[(long)(lo + p) * 8 + h] * ALPHA;
        }
        uint4 fv = *reinterpret_cast<const uint4*>(&featb[(long)s * 256 + t * 8]);
        const uint* fp = reinterpret_cast<const uint*>(&fv);
#pragma unroll
        for (int q = 0; q < 4; ++q) {
            uint u = fp[q];
            acc[2 * q]     += __uint_as_float(u << 16) * a;
            acc[2 * q + 1] += __uint_as_float(u & 0xffff0000u) * a;
        }
    }
#pragma unroll
    for (int k = 0; k < 8; ++k) acc[k] += __shfl_down(acc[k], 32);
    if (half == 0) {
        ushort8v o;
#pragma unroll
        for (int k = 0; k < 8; ++k) {
            float v = acc[k];
            v = v > 0.f ? v : __expf(v) - 1.f;
            o[k] = f2b(v);
        }
        *reinterpret_cast<ushort8v*>(&outb[(long)d * 256 + t * 8]) = o;
    }
}

// ---------------- fused edge kernel, H=1, OUT=16, f32 feat, no ELU ----------------

__global__ __launch_bounds__(64) void fused_edge_h1(
    const int* __restrict__ offsets, const int* __restrict__ src_s,
    const int* __restrict__ et_s,
    const float* __restrict__ el, const float* __restrict__ er,
    const float* __restrict__ etatt,
    const float* __restrict__ feat, float* __restrict__ out, int N) {
    int d = blockIdx.x;
    int lane = threadIdx.x;
    int lo = offsets[d], hi = offsets[d + 1];
    int deg = hi - lo;
    __shared__ float a_lds[512];
    __shared__ float stats[2];
    float er_d = er[d];
    bool fast = (deg <= 512);
    if (fast) {
        for (int i = lane; i < deg; i += 64) {
            int s = src_s[lo + i], t = et_s[lo + i];
            float v = el[s] + er_d + etatt[t];
            a_lds[i] = v > 0.f ? v : SLOPE * v;
        }
        __syncthreads();
        {
            float m = -INFINITY;
            for (int i = lane; i < deg; i += 64) m = fmaxf(m, a_lds[i]);
#pragma unroll
            for (int off = 1; off < 64; off <<= 1) m = fmaxf(m, __shfl_xor(m, off, 64));
            float ssum = 0.f;
            for (int i = lane; i < deg; i += 64) ssum += __expf(a_lds[i] - m);
#pragma unroll
            for (int off = 1; off < 64; off <<= 1) ssum += __shfl_xor(ssum, off, 64);
            if (lane == 0) {
                stats[0] = m;
                stats[1] = ssum > 0.f ? 1.f / ssum : 0.f;
            }
        }
        __syncthreads();
        for (int i = lane; i < deg; i += 64) a_lds[i] = __expf(a_lds[i] - stats[0]) * stats[1];
        __syncthreads();
    } else {
        float m = -INFINITY;
        for (int i = lane; i < deg; i += 64) {
            int s = src_s[lo + i], t = et_s[lo + i];
            float v = el[s] + er_d + etatt[t];
            v = v > 0.f ? v : SLOPE * v;
            m = fmaxf(m, v);
        }
#pragma unroll
        for (int off = 1; off < 64; off <<= 1) m = fmaxf(m, __shfl_xor(m, off, 64));
        float ssum = 0.f;
        for (int i = lane; i < deg; i += 64) {
            int s = src_s[lo + i], t = et_s[lo + i];
            float v = el[s] + er_d + etatt[t];
            v = v > 0.f ? v : SLOPE * v;
            ssum += __expf(v - m);
        }
#pragma unroll
        for (int off = 1; off < 64; off <<= 1) ssum += __shfl_xor(ssum, off, 64);
        if (lane == 0) {
            stats[0] = m;
            stats[1] = ssum > 0.f ? 1.f / ssum : 0.f;
        }
        __syncthreads();
    }
    int g = lane >> 2, t = lane & 3;
    float4 acc = {0.f, 0.f, 0.f, 0.f};
    for (int p = g; p < deg; p += 16) {
        int s = src_s[lo + p];
        float a;
        if (fast) a = a_lds[p];
        else {
            int tt = et_s[lo + p];
            float v = el[s] + er_d + etatt[tt];
            v = v > 0.f ? v : SLOPE * v;
            a = __expf(v - stats[0]) * stats[1];
        }
        float4 f = *reinterpret_cast<const float4*>(&feat[(long)s * 16 + t * 4]);
        acc.x += f.x * a;
        acc.y += f.y * a;
        acc.z += f.z * a;
        acc.w += f.w * a;
    }
#pragma unroll
    for (int off = 4; off < 64; off <<= 1) {
        acc.x += __shfl_down(acc.x, off);
        acc.y += __shfl_down(acc.y, off);
        acc.z += __shfl_down(acc.z, off);
        acc.w += __shfl_down(acc.w, off);
    }
    if (lane < 4) *reinterpret_cast<float4*>(&out[(long)d * 16 + t * 4]) = acc;
}

// ---------------- launch ----------------

extern "C" void kernel_launch(void* const* d_in, const int* in_sizes, int n_in,
                              void* d_out, int out_size, void* d_ws, size_t ws_size,
                              hipStream_t stream) {
    const float* x0   = (const float*)d_in[0];
    const float* x1   = (const float*)d_in[1];
    const float* x2   = (const float*)d_in[2];
    const float* fcw0 = (const float*)d_in[3];
    const float* fcb0 = (const float*)d_in[4];
    const float* fcw1 = (const float*)d_in[5];
    const float* fcb1 = (const float*)d_in[6];
    const float* fcw2 = (const float*)d_in[7];
    const float* fcb2 = (const float*)d_in[8];
    const float* W0   = (const float*)d_in[9];
    const float* We0  = (const float*)d_in[10];
    const float* eemb0= (const float*)d_in[11];
    const float* al0  = (const float*)d_in[12];
    const float* ar0  = (const float*)d_in[13];
    const float* ae0  = (const float*)d_in[14];
    const float* W1   = (const float*)d_in[15];
    const float* We1  = (const float*)d_in[16];
    const float* eemb1= (const float*)d_in[17];
    const float* al1  = (const float*)d_in[18];
    const float* ar1  = (const float*)d_in[19];
    const float* ae1  = (const float*)d_in[20];
    const float* resW1= (const float*)d_in[21];
    const float* W2   = (const float*)d_in[22];
    const float* We2  = (const float*)d_in[23];
    const float* eemb2= (const float*)d_in[24];
    const float* al2  = (const float*)d_in[25];
    const float* ar2  = (const float*)d_in[26];
    const float* ae2  = (const float*)d_in[27];
    const float* resW2= (const float*)d_in[28];
    const int* src    = (const int*)d_in[29];
    const int* dst    = (const int*)d_in[30];
    const int* etype  = (const int*)d_in[31];

    const int n0 = in_sizes[0] / 128;
    const int n1 = in_sizes[1] / 256;
    const int n2 = in_sizes[2] / 64;
    const int N  = n0 + n1 + n2;
    const int E  = in_sizes[29];

    char* w = (char*)d_ws;
    auto alloc = [&](size_t bytes) {
        char* p = w;
        w += (bytes + 255) & ~(size_t)255;
        return p;
    };
    int*    counts  = (int*)alloc((size_t)N * 4);
    int*    offsets = (int*)alloc((size_t)(N + 1) * 4);
    int*    cursor  = (int*)alloc((size_t)N * 4);
    int*    partial = (int*)alloc(1024 * 4);
    int*    src_s   = (int*)alloc((size_t)E * 4);
    int*    et_s    = (int*)alloc((size_t)E * 4);
    ushort* h2res   = (ushort*)alloc((size_t)N * 256 * 2);
    float*  a0f     = (float*)alloc((size_t)E * 8 * 4);
    ushort* h0bf    = (ushort*)alloc((size_t)N * 64 * 2);
    ushort* featb   = (ushort*)alloc((size_t)N * 256 * 2);
    ushort* h1bf    = (ushort*)alloc((size_t)N * 256 * 2);
    ushort* h2bf    = (ushort*)alloc((size_t)N * 256 * 2);
    float*  el      = (float*)alloc((size_t)N * 8 * 4);
    float*  er      = (float*)alloc((size_t)N * 8 * 4);
    float*  etatt   = (float*)alloc(6 * 8 * 4);
    ushort* Wt0     = (ushort*)alloc((size_t)256 * 64 * 2);
    ushort* Wt1     = (ushort*)alloc((size_t)256 * 256 * 2);
    ushort* WtR     = (ushort*)alloc((size_t)256 * 256 * 2);
    float*  feat2   = (float*)alloc((size_t)N * 16 * 4);
    float*  out     = (float*)d_out;

    const int TB = 256;
    int eb = (E + TB - 1) / TB;
    int nb1 = (N + 255) / 256;

    // ---- CSR build ----
    hipMemsetAsync(counts, 0, (size_t)N * 4, stream);
    hist_kernel<<<eb, TB, 0, stream>>>(dst, counts, E);
    scan_part<<<nb1, 256, 0, stream>>>(counts, offsets, partial, N);
    scan_top<<<1, 256, 0, stream>>>(partial, nb1);
    scan_add<<<nb1, 256, 0, stream>>>(offsets, partial, N);
    hipMemcpyAsync(cursor, offsets, (size_t)N * 4, hipMemcpyDeviceToDevice, stream);
    scatter_kernel<<<eb, TB, 0, stream>>>(src, dst, etype, cursor, src_s, et_s, E);

    // ---- weight prep ----
    wprep<<<(64 * 256 + TB - 1) / TB, TB, 0, stream>>>(W0, Wt0, 64, 256);
    wprep<<<(256 * 256 + TB - 1) / TB, TB, 0, stream>>>(W1, Wt1, 256, 256);
    wprep<<<(256 * 256 + TB - 1) / TB, TB, 0, stream>>>(resW1, WtR, 256, 256);

    // ---- input FC: h0bf = concat(x_i @ fcw_i + fcb_i) ----
    {
        dim3 g0(1, (n0 + 63) / 64);
        matmul64_fc<<<g0, TB, 0, stream>>>(x0, fcw0, fcb0, h0bf, n0, 128, 64);
        dim3 g1(1, (n1 + 63) / 64);
        matmul64_fc<<<g1, TB, 0, stream>>>(x1, fcw1, fcb1, h0bf + (long)n0 * 64, n1, 256, 64);
        dim3 g2(1, (n2 + 63) / 64);
        matmul64_fc<<<g2, TB, 0, stream>>>(x2, fcw2, fcb2, h0bf + (long)(n0 + n1) * 64, n2, 64, 64);
    }

    int nb_nh8 = (N * 8 + TB - 1) / TB;
    dim3 gg(256 / 128, (N + 127) / 128);

    // ---- layer 0 ----
    {
        gemm_bf16<<<gg, TB, 0, stream>>>(h0bf, Wt0, featb, N, 256, 64);
        attn_lr_b<8, 32><<<nb_nh8, TB, 0, stream>>>(featb, al0, ar0, el, er, N);
        etype_att<8><<<6, 512, 0, stream>>>(eemb0, We0, ae0, etatt);
        fused_edge_h8<false, true, false><<<N, 64, 0, stream>>>(
            offsets, src_s, et_s, el, er, etatt, featb, nullptr, a0f, nullptr, h1bf, N);
    }

    // ---- layer 1 ----
    {
        gemm_bf16<<<gg, TB, 0, stream>>>(h1bf, Wt1, featb, N, 256, 256);
        attn_lr_b<8, 32><<<nb_nh8, TB, 0, stream>>>(featb, al1, ar1, el, er, N);
        etype_att<8><<<6, 512, 0, stream>>>(eemb1, We1, ae1, etatt);
        gemm_bf16<<<gg, TB, 0, stream>>>(h1bf, WtR, h2res, N, 256, 256);
        fused_edge_h8<true, false, true><<<N, 64, 0, stream>>>(
            offsets, src_s, et_s, el, er, etatt, featb, a0f, nullptr, h2res, h2bf, N);
    }

    // ---- layer 2 (H=1, OUT=16, residual, no activation) ----
    {
        matmul_n16b<false><<<(N + 15) / 16, TB, 0, stream>>>(h2bf, W2, feat2, N, 256);
        int nb_nh1 = (N + TB - 1) / TB;
        attn_lr<1, 16><<<nb_nh1, TB, 0, stream>>>(feat2, al2, ar2, el, er, N);
        etype_att<1><<<6, 64, 0, stream>>>(eemb2, We2, ae2, etatt);
        fused_edge_h1<<<N, 64, 0, stream>>>(offsets, src_s, et_s, el, er, etatt, feat2, out, N);
        matmul_n16b<true><<<(N + 15) / 16, TB, 0, stream>>>(h2bf, resW2, out, N, 256);
    }
}

// Round 7
// 499.573 us; speedup vs baseline: 2.7039x; 1.0219x over previous
//
#include <hip/hip_runtime.h>
#include <hip/hip_bf16.h>

#define ALPHA 0.05f
#define SLOPE 0.2f
#define LCAP 128

typedef __attribute__((ext_vector_type(8))) short short8v;
typedef __attribute__((ext_vector_type(8))) unsigned short ushort8v;
typedef __attribute__((ext_vector_type(4))) float floatx4;

__device__ inline ushort f2b(float f) {
    uint u = __float_as_uint(f);
    return (ushort)((u + 0x7fffu + ((u >> 16) & 1u)) >> 16);
}
__device__ inline float b2f(ushort b) { return __uint_as_float(((uint)b) << 16); }

// ---------------- CSR build ----------------

__global__ void hist_kernel(const int* __restrict__ dst, int* __restrict__ counts, int E) {
    int e = blockIdx.x * blockDim.x + threadIdx.x;
    if (e < E) atomicAdd(&counts[dst[e]], 1);
}

__global__ __launch_bounds__(256) void scan_part(const int* __restrict__ counts,
                                                 int* __restrict__ offsets,
                                                 int* __restrict__ partial, int n) {
    __shared__ int sd[256];
    int i = blockIdx.x * 256 + threadIdx.x;
    int v = (i < n) ? counts[i] : 0;
    sd[threadIdx.x] = v;
    __syncthreads();
    for (int off = 1; off < 256; off <<= 1) {
        int t = (threadIdx.x >= off) ? sd[threadIdx.x - off] : 0;
        __syncthreads();
        sd[threadIdx.x] += t;
        __syncthreads();
    }
    if (i < n) offsets[i + 1] = sd[threadIdx.x];
    if (threadIdx.x == 255) partial[blockIdx.x] = sd[255];
}

__global__ __launch_bounds__(256) void scan_top(int* __restrict__ partial, int nb) {
    __shared__ int sd[256];
    int v = (threadIdx.x < nb) ? partial[threadIdx.x] : 0;
    sd[threadIdx.x] = v;
    __syncthreads();
    for (int off = 1; off < 256; off <<= 1) {
        int t = (threadIdx.x >= off) ? sd[threadIdx.x - off] : 0;
        __syncthreads();
        sd[threadIdx.x] += t;
        __syncthreads();
    }
    if (threadIdx.x < nb) partial[threadIdx.x] = sd[threadIdx.x];
}

__global__ __launch_bounds__(256) void scan_add(int* __restrict__ offsets,
                                                const int* __restrict__ partial, int n) {
    int i = blockIdx.x * 256 + threadIdx.x;
    if (i == 0) offsets[0] = 0;
    if (blockIdx.x > 0 && i < n) offsets[i + 1] += partial[blockIdx.x - 1];
}

__global__ void scatter_kernel(const int* __restrict__ src, const int* __restrict__ dst,
                               const int* __restrict__ et, int* __restrict__ cursor,
                               int* __restrict__ src_s, int* __restrict__ et_s, int E) {
    int e = blockIdx.x * blockDim.x + threadIdx.x;
    if (e >= E) return;
    int d = dst[e];
    int pos = atomicAdd(&cursor[d], 1);
    src_s[pos] = src[e];
    et_s[pos]  = et[e];
}

// ---------------- weight prep: W[K][N] f32 -> Wt[N][K] bf16 ----------------

__global__ void wprep(const float* __restrict__ W, ushort* __restrict__ Wt, int K, int N) {
    int i = blockIdx.x * blockDim.x + threadIdx.x;
    if (i >= K * N) return;
    int k = i / N, n = i % N;
    Wt[(long)n * K + k] = f2b(W[i]);
}

// ---------------- bf16 MFMA GEMM: C[M,N] = A[M,K] @ Bt[N,K]^T, bf16 out ----------------

__global__ __launch_bounds__(256) void gemm_bf16(const ushort* __restrict__ A,
                                                 const ushort* __restrict__ Bt,
                                                 ushort* __restrict__ Cb,
                                                 int M, int N, int K) {
    __shared__ ushort As[128][40];
    __shared__ ushort Bs[128][40];
    int bm = blockIdx.y * 128, bn = blockIdx.x * 128;
    int tid = threadIdx.x;
    int wave = tid >> 6, lane = tid & 63;
    int wm = (wave >> 1) * 64, wn = (wave & 1) * 64;
    floatx4 acc[4][4] = {};
    for (int k0 = 0; k0 < K; k0 += 32) {
#pragma unroll
        for (int it = 0; it < 2; ++it) {
            int idx = (tid + it * 256) * 8;
            int r = idx >> 5, c = idx & 31;
            int gr = bm + r;
            uint4 va = {0u, 0u, 0u, 0u};
            if (gr < M) va = *reinterpret_cast<const uint4*>(&A[(long)gr * K + k0 + c]);
            *reinterpret_cast<uint4*>(&As[r][c]) = va;
            uint4 vb = *reinterpret_cast<const uint4*>(&Bt[(long)(bn + r) * K + k0 + c]);
            *reinterpret_cast<uint4*>(&Bs[r][c]) = vb;
        }
        __syncthreads();
        int lr = lane & 15, lk = (lane >> 4) * 8;
        short8v af[4], bfr[4];
#pragma unroll
        for (int i = 0; i < 4; ++i)
            af[i] = *reinterpret_cast<const short8v*>(&As[wm + i * 16 + lr][lk]);
#pragma unroll
        for (int j = 0; j < 4; ++j)
            bfr[j] = *reinterpret_cast<const short8v*>(&Bs[wn + j * 16 + lr][lk]);
#pragma unroll
        for (int i = 0; i < 4; ++i)
#pragma unroll
            for (int j = 0; j < 4; ++j)
                acc[i][j] = __builtin_amdgcn_mfma_f32_16x16x32_bf16(af[i], bfr[j], acc[i][j], 0, 0, 0);
        __syncthreads();
    }
    int col = lane & 15, rbase = (lane >> 4) * 4;
#pragma unroll
    for (int i = 0; i < 4; ++i) {
#pragma unroll
        for (int r = 0; r < 4; ++r) {
            int gm = bm + wm + i * 16 + rbase + r;
            if (gm >= M) continue;
#pragma unroll
            for (int j = 0; j < 4; ++j) {
                int gn = bn + wn + j * 16 + col;
                Cb[(long)gm * N + gn] = f2b(acc[i][j][r]);
            }
        }
    }
}

// ---------------- input FC (f32 compute, bf16 out): C[M,64] = A@W + b ----------------

__global__ __launch_bounds__(256) void matmul64_fc(const float* __restrict__ A,
                                                   const float* __restrict__ W,
                                                   const float* __restrict__ bias,
                                                   ushort* __restrict__ C,
                                                   int M, int K, int N) {
    __shared__ float As[16][68];
    __shared__ float Bs[16][68];
    int bm = blockIdx.y * 64, bn = blockIdx.x * 64;
    int tx = threadIdx.x % 16, ty = threadIdx.x / 16;
    float acc[4][4] = {};
    for (int k0 = 0; k0 < K; k0 += 16) {
        for (int i = threadIdx.x; i < 64 * 16; i += 256) {
            int mm = i / 16, kk = i % 16;
            int gm = bm + mm;
            As[kk][mm] = (gm < M) ? A[(long)gm * K + k0 + kk] : 0.f;
        }
        for (int i = threadIdx.x; i < 16 * 64; i += 256) {
            int kk = i / 64, nn = i % 64;
            Bs[kk][nn] = W[(long)(k0 + kk) * N + bn + nn];
        }
        __syncthreads();
#pragma unroll
        for (int kk = 0; kk < 16; ++kk) {
            float a[4], b[4];
#pragma unroll
            for (int i = 0; i < 4; ++i) a[i] = As[kk][ty * 4 + i];
#pragma unroll
            for (int j = 0; j < 4; ++j) b[j] = Bs[kk][tx * 4 + j];
#pragma unroll
            for (int i = 0; i < 4; ++i)
#pragma unroll
                for (int j = 0; j < 4; ++j) acc[i][j] += a[i] * b[j];
        }
        __syncthreads();
    }
#pragma unroll
    for (int i = 0; i < 4; ++i) {
        int gm = bm + ty * 4 + i;
        if (gm >= M) continue;
#pragma unroll
        for (int j = 0; j < 4; ++j) {
            int gn = bn + tx * 4 + j;
            C[(long)gm * N + gn] = f2b(acc[i][j] + bias[gn]);
        }
    }
}

// ---------------- small N=16 matmul, bf16 A: C[M,16] = A[M,K] @ W[K,16] (+=) ----------------

template<bool ACC>
__global__ __launch_bounds__(256) void matmul_n16b(const ushort* __restrict__ A,
                                                   const float* __restrict__ W,
                                                   float* __restrict__ C, int M, int K) {
    __shared__ float Ws[256 * 16];
    for (int i = threadIdx.x; i < K * 16; i += 256) Ws[i] = W[i];
    __syncthreads();
    int m = blockIdx.x * 16 + threadIdx.x / 16;
    int nn = threadIdx.x % 16;
    if (m >= M) return;
    float s = 0.f;
    for (int k8 = 0; k8 < K / 8; ++k8) {
        uint4 v = *reinterpret_cast<const uint4*>(&A[(long)m * K + k8 * 8]);
        const uint* vp = reinterpret_cast<const uint*>(&v);
#pragma unroll
        for (int q = 0; q < 4; ++q) {
            uint w2 = vp[q];
            float f0 = __uint_as_float((w2 & 0xffffu) << 16);
            float f1 = __uint_as_float(w2 & 0xffff0000u);
            int k = k8 * 8 + q * 2;
            s += f0 * Ws[(k + 0) * 16 + nn] + f1 * Ws[(k + 1) * 16 + nn];
        }
    }
    if (ACC) s += C[(long)m * 16 + nn];
    C[(long)m * 16 + nn] = s;
}

// ---------------- attention pieces ----------------

// f32-feat version (layer 2)
template<int H, int OUT>
__global__ void attn_lr(const float* __restrict__ feat, const float* __restrict__ al,
                        const float* __restrict__ ar, float* __restrict__ el,
                        float* __restrict__ er, int N) {
    int gid = blockIdx.x * blockDim.x + threadIdx.x;
    int n = gid / H, h = gid % H;
    if (n >= N) return;
    const float* fr = feat + (long)n * H * OUT + h * OUT;
    float sl = 0.f, sr = 0.f;
#pragma unroll
    for (int o = 0; o < OUT; ++o) {
        float f = fr[o];
        sl += f * al[h * OUT + o];
        sr += f * ar[h * OUT + o];
    }
    el[n * H + h] = sl;
    er[n * H + h] = sr;
}

// bf16-feat version (layers 0/1)
template<int H, int OUT>
__global__ void attn_lr_b(const ushort* __restrict__ feat, const float* __restrict__ al,
                          const float* __restrict__ ar, float* __restrict__ el,
                          float* __restrict__ er, int N) {
    int gid = blockIdx.x * blockDim.x + threadIdx.x;
    int n = gid / H, h = gid % H;
    if (n >= N) return;
    const ushort* fr = feat + (long)n * H * OUT + h * OUT;
    float sl = 0.f, sr = 0.f;
#pragma unroll
    for (int q = 0; q < OUT / 8; ++q) {
        uint4 v = *reinterpret_cast<const uint4*>(&fr[q * 8]);
        const uint* vp = reinterpret_cast<const uint*>(&v);
#pragma unroll
        for (int i = 0; i < 4; ++i) {
            float f0 = __uint_as_float((vp[i] & 0xffffu) << 16);
            float f1 = __uint_as_float(vp[i] & 0xffff0000u);
            int o = q * 8 + i * 2;
            sl += f0 * al[h * OUT + o] + f1 * al[h * OUT + o + 1];
            sr += f0 * ar[h * OUT + o] + f1 * ar[h * OUT + o + 1];
        }
    }
    el[n * H + h] = sl;
    er[n * H + h] = sr;
}

// et_att[t,h] = sum_d (eemb[t] @ We)[h*64+d] * ae[h,d]
template<int H>
__global__ __launch_bounds__(H * 64) void etype_att(const float* __restrict__ eemb,
                                                    const float* __restrict__ We,
                                                    const float* __restrict__ ae,
                                                    float* __restrict__ out) {
    __shared__ float es[64];
    int t = blockIdx.x;
    int j = threadIdx.x;               // j = h*64 + d
    if (j < 64) es[j] = eemb[t * 64 + j];
    __syncthreads();
    float wsum = 0.f;
#pragma unroll 8
    for (int k = 0; k < 64; ++k) wsum += es[k] * We[k * (H * 64) + j];
    float v = wsum * ae[j];
#pragma unroll
    for (int off = 32; off > 0; off >>= 1) v += __shfl_down(v, off, 64);
    if ((j & 63) == 0) out[t * H + (j >> 6)] = v;
}

// ---------------- fused logits+softmax+aggregate, H=8, OUT=32, bf16 feat ----------------
// one block (64 threads = 1 wave) per dst node

template<bool BLEND, bool SAVE, bool RES>
__global__ __launch_bounds__(64) void fused_edge_h8(
    const int* __restrict__ offsets, const int* __restrict__ src_s,
    const int* __restrict__ et_s,
    const float* __restrict__ el, const float* __restrict__ er,
    const float* __restrict__ etatt,
    const ushort* __restrict__ featb,
    const ushort* __restrict__ a0_in, ushort* __restrict__ a0_out,
    const ushort* __restrict__ resin, ushort* __restrict__ outb, int N) {
    int d = blockIdx.x;
    int lane = threadIdx.x;
    int lo = offsets[d], hi = offsets[d + 1];
    int deg = hi - lo;
    __shared__ float a_lds[LCAP][8];
    __shared__ int   s_lds[LCAP];
    __shared__ float er_s[8];
    __shared__ float m_s[8], inv_s[8];
    if (lane < 8) er_s[lane] = er[d * 8 + lane];
    __syncthreads();
    bool fast = (deg <= LCAP);
    if (fast) {
        for (int i = lane; i < deg * 8; i += 64) {
            int p = i >> 3, h = i & 7;
            int s = src_s[lo + p], t = et_s[lo + p];
            if (h == 0) s_lds[p] = s;
            float v = el[s * 8 + h] + er_s[h] + etatt[t * 8 + h];
            a_lds[p][h] = v > 0.f ? v : SLOPE * v;
        }
        __syncthreads();
        {
            // wave-parallel softmax stats: lane = g*8 + h
            int g = lane >> 3, h = lane & 7;
            float m = -INFINITY;
            for (int p = g; p < deg; p += 8) m = fmaxf(m, a_lds[p][h]);
#pragma unroll
            for (int off = 8; off < 64; off <<= 1) m = fmaxf(m, __shfl_xor(m, off, 64));
            float ssum = 0.f;
            for (int p = g; p < deg; p += 8) ssum += __expf(a_lds[p][h] - m);
#pragma unroll
            for (int off = 8; off < 64; off <<= 1) ssum += __shfl_xor(ssum, off, 64);
            if (g == 0) {
                m_s[h] = m;
                inv_s[h] = ssum > 0.f ? 1.f / ssum : 0.f;
            }
        }
        __syncthreads();
        for (int i = lane; i < deg * 8; i += 64) {
            int p = i >> 3, h = i & 7;
            float a = __expf(a_lds[p][h] - m_s[h]) * inv_s[h];
            if (BLEND) a = a * (1.f - ALPHA) + b2f(a0_in[lo * 8 + i]) * ALPHA;
            a_lds[p][h] = a;
            if (SAVE) a0_out[lo * 8 + i] = f2b(a);
        }
        __syncthreads();
    } else {
        // fallback: recompute logits (rare; any degree)
        int g = lane >> 3, h = lane & 7;
        float m = -INFINITY;
        for (int p = g; p < deg; p += 8) {
            int s = src_s[lo + p], t = et_s[lo + p];
            float v = el[s * 8 + h] + er_s[h] + etatt[t * 8 + h];
            v = v > 0.f ? v : SLOPE * v;
            m = fmaxf(m, v);
        }
#pragma unroll
        for (int off = 8; off < 64; off <<= 1) m = fmaxf(m, __shfl_xor(m, off, 64));
        float ssum = 0.f;
        for (int p = g; p < deg; p += 8) {
            int s = src_s[lo + p], t = et_s[lo + p];
            float v = el[s * 8 + h] + er_s[h] + etatt[t * 8 + h];
            v = v > 0.f ? v : SLOPE * v;
            ssum += __expf(v - m);
        }
#pragma unroll
        for (int off = 8; off < 64; off <<= 1) ssum += __shfl_xor(ssum, off, 64);
        if (g == 0) {
            m_s[h] = m;
            inv_s[h] = ssum > 0.f ? 1.f / ssum : 0.f;
        }
        __syncthreads();
        if (SAVE) {
            for (int i = lane; i < deg * 8; i += 64) {
                int p = i >> 3, hh = i & 7;
                int s = src_s[lo + p], t = et_s[lo + p];
                float v = el[s * 8 + hh] + er_s[hh] + etatt[t * 8 + hh];
                v = v > 0.f ? v : SLOPE * v;
                float a = __expf(v - m_s[hh]) * inv_s[hh];
                if (BLEND) a = a * (1.f - ALPHA) + b2f(a0_in[lo * 8 + i]) * ALPHA;
                a0_out[lo * 8 + i] = f2b(a);
            }
        }
    }
    // aggregation: 2 edges in flight (half-wave each), 16B loads, uint-pair unpack
    int half = lane >> 5, t = lane & 31;
    float acc[8];
#pragma unroll
    for (int k = 0; k < 8; ++k) acc[k] = 0.f;
    if (RES && half == 0) {
        uint4 rv = *reinterpret_cast<const uint4*>(&resin[(long)d * 256 + t * 8]);
        const uint* rp = reinterpret_cast<const uint*>(&rv);
#pragma unroll
        for (int q = 0; q < 4; ++q) {
            acc[2 * q]     = __uint_as_float(rp[q] << 16);
            acc[2 * q + 1] = __uint_as_float(rp[q] & 0xffff0000u);
        }
    }
    int h = t >> 2;
    if (fast) {
        // 4-edge unroll per half-wave: 4 independent gathers in flight
        int p = half;
        for (; p + 6 < deg; p += 8) {
            int s0 = s_lds[p],     s1 = s_lds[p + 2];
            int s2 = s_lds[p + 4], s3 = s_lds[p + 6];
            float a0 = a_lds[p][h],     a1 = a_lds[p + 2][h];
            float a2 = a_lds[p + 4][h], a3 = a_lds[p + 6][h];
            uint4 f0 = *reinterpret_cast<const uint4*>(&featb[(long)s0 * 256 + t * 8]);
            uint4 f1 = *reinterpret_cast<const uint4*>(&featb[(long)s1 * 256 + t * 8]);
            uint4 f2 = *reinterpret_cast<const uint4*>(&featb[(long)s2 * 256 + t * 8]);
            uint4 f3 = *reinterpret_cast<const uint4*>(&featb[(long)s3 * 256 + t * 8]);
            const uint* q0 = reinterpret_cast<const uint*>(&f0);
            const uint* q1 = reinterpret_cast<const uint*>(&f1);
            const uint* q2 = reinterpret_cast<const uint*>(&f2);
            const uint* q3 = reinterpret_cast<const uint*>(&f3);
#pragma unroll
            for (int q = 0; q < 4; ++q) {
                acc[2 * q] += __uint_as_float(q0[q] << 16) * a0
                            + __uint_as_float(q1[q] << 16) * a1
                            + __uint_as_float(q2[q] << 16) * a2
                            + __uint_as_float(q3[q] << 16) * a3;
                acc[2 * q + 1] += __uint_as_float(q0[q] & 0xffff0000u) * a0
                                + __uint_as_float(q1[q] & 0xffff0000u) * a1
                                + __uint_as_float(q2[q] & 0xffff0000u) * a2
                                + __uint_as_float(q3[q] & 0xffff0000u) * a3;
            }
        }
        for (; p < deg; p += 2) {
            int s = s_lds[p];
            float a = a_lds[p][h];
            uint4 fv = *reinterpret_cast<const uint4*>(&featb[(long)s * 256 + t * 8]);
            const uint* fp = reinterpret_cast<const uint*>(&fv);
#pragma unroll
            for (int q = 0; q < 4; ++q) {
                uint u = fp[q];
                acc[2 * q]     += __uint_as_float(u << 16) * a;
                acc[2 * q + 1] += __uint_as_float(u & 0xffff0000u) * a;
            }
        }
    } else {
        for (int p = half; p < deg; p += 2) {
            int s = src_s[lo + p];
            int tt = et_s[lo + p];
            float v = el[s * 8 + h] + er_s[h] + etatt[tt * 8 + h];
            v = v > 0.f ? v : SLOPE * v;
            float a = __expf(v - m_s[h]) * inv_s[h];
            if (BLEND) a = a * (1.f - ALPHA) + b2f(a0_in[(long)(lo + p) * 8 + h]) * ALPHA;
            uint4 fv = *reinterpret_cast<const uint4*>(&featb[(long)s * 256 + t * 8]);
            const uint* fp = reinterpret_cast<const uint*>(&fv);
#pragma unroll
            for (int q = 0; q < 4; ++q) {
                uint u = fp[q];
                acc[2 * q]     += __uint_as_float(u << 16) * a;
                acc[2 * q + 1] += __uint_as_float(u & 0xffff0000u) * a;
            }
        }
    }
#pragma unroll
    for (int k = 0; k < 8; ++k) acc[k] += __shfl_down(acc[k], 32);
    if (half == 0) {
        ushort8v o;
#pragma unroll
        for (int k = 0; k < 8; ++k) {
            float v = acc[k];
            v = v > 0.f ? v : __expf(v) - 1.f;
            o[k] = f2b(v);
        }
        *reinterpret_cast<ushort8v*>(&outb[(long)d * 256 + t * 8]) = o;
    }
}

// ---------------- fused edge kernel, H=1, OUT=16, f32 feat, no ELU ----------------

__global__ __launch_bounds__(64) void fused_edge_h1(
    const int* __restrict__ offsets, const int* __restrict__ src_s,
    const int* __restrict__ et_s,
    const float* __restrict__ el, const float* __restrict__ er,
    const float* __restrict__ etatt,
    const float* __restrict__ feat, float* __restrict__ out, int N) {
    int d = blockIdx.x;
    int lane = threadIdx.x;
    int lo = offsets[d], hi = offsets[d + 1];
    int deg = hi - lo;
    __shared__ float a_lds[512];
    __shared__ float stats[2];
    float er_d = er[d];
    bool fast = (deg <= 512);
    if (fast) {
        for (int i = lane; i < deg; i += 64) {
            int s = src_s[lo + i], t = et_s[lo + i];
            float v = el[s] + er_d + etatt[t];
            a_lds[i] = v > 0.f ? v : SLOPE * v;
        }
        __syncthreads();
        {
            float m = -INFINITY;
            for (int i = lane; i < deg; i += 64) m = fmaxf(m, a_lds[i]);
#pragma unroll
            for (int off = 1; off < 64; off <<= 1) m = fmaxf(m, __shfl_xor(m, off, 64));
            float ssum = 0.f;
            for (int i = lane; i < deg; i += 64) ssum += __expf(a_lds[i] - m);
#pragma unroll
            for (int off = 1; off < 64; off <<= 1) ssum += __shfl_xor(ssum, off, 64);
            if (lane == 0) {
                stats[0] = m;
                stats[1] = ssum > 0.f ? 1.f / ssum : 0.f;
            }
        }
        __syncthreads();
        for (int i = lane; i < deg; i += 64) a_lds[i] = __expf(a_lds[i] - stats[0]) * stats[1];
        __syncthreads();
    } else {
        float m = -INFINITY;
        for (int i = lane; i < deg; i += 64) {
            int s = src_s[lo + i], t = et_s[lo + i];
            float v = el[s] + er_d + etatt[t];
            v = v > 0.f ? v : SLOPE * v;
            m = fmaxf(m, v);
        }
#pragma unroll
        for (int off = 1; off < 64; off <<= 1) m = fmaxf(m, __shfl_xor(m, off, 64));
        float ssum = 0.f;
        for (int i = lane; i < deg; i += 64) {
            int s = src_s[lo + i], t = et_s[lo + i];
            float v = el[s] + er_d + etatt[t];
            v = v > 0.f ? v : SLOPE * v;
            ssum += __expf(v - m);
        }
#pragma unroll
        for (int off = 1; off < 64; off <<= 1) ssum += __shfl_xor(ssum, off, 64);
        if (lane == 0) {
            stats[0] = m;
            stats[1] = ssum > 0.f ? 1.f / ssum : 0.f;
        }
        __syncthreads();
    }
    int g = lane >> 2, t = lane & 3;
    float4 acc = {0.f, 0.f, 0.f, 0.f};
    for (int p = g; p < deg; p += 16) {
        int s = src_s[lo + p];
        float a;
        if (fast) a = a_lds[p];
        else {
            int tt = et_s[lo + p];
            float v = el[s] + er_d + etatt[tt];
            v = v > 0.f ? v : SLOPE * v;
            a = __expf(v - stats[0]) * stats[1];
        }
        float4 f = *reinterpret_cast<const float4*>(&feat[(long)s * 16 + t * 4]);
        acc.x += f.x * a;
        acc.y += f.y * a;
        acc.z += f.z * a;
        acc.w += f.w * a;
    }
#pragma unroll
    for (int off = 4; off < 64; off <<= 1) {
        acc.x += __shfl_down(acc.x, off);
        acc.y += __shfl_down(acc.y, off);
        acc.z += __shfl_down(acc.z, off);
        acc.w += __shfl_down(acc.w, off);
    }
    if (lane < 4) *reinterpret_cast<float4*>(&out[(long)d * 16 + t * 4]) = acc;
}

// ---------------- launch ----------------

extern "C" void kernel_launch(void* const* d_in, const int* in_sizes, int n_in,
                              void* d_out, int out_size, void* d_ws, size_t ws_size,
                              hipStream_t stream) {
    const float* x0   = (const float*)d_in[0];
    const float* x1   = (const float*)d_in[1];
    const float* x2   = (const float*)d_in[2];
    const float* fcw0 = (const float*)d_in[3];
    const float* fcb0 = (const float*)d_in[4];
    const float* fcw1 = (const float*)d_in[5];
    const float* fcb1 = (const float*)d_in[6];
    const float* fcw2 = (const float*)d_in[7];
    const float* fcb2 = (const float*)d_in[8];
    const float* W0   = (const float*)d_in[9];
    const float* We0  = (const float*)d_in[10];
    const float* eemb0= (const float*)d_in[11];
    const float* al0  = (const float*)d_in[12];
    const float* ar0  = (const float*)d_in[13];
    const float* ae0  = (const float*)d_in[14];
    const float* W1   = (const float*)d_in[15];
    const float* We1  = (const float*)d_in[16];
    const float* eemb1= (const float*)d_in[17];
    const float* al1  = (const float*)d_in[18];
    const float* ar1  = (const float*)d_in[19];
    const float* ae1  = (const float*)d_in[20];
    const float* resW1= (const float*)d_in[21];
    const float* W2   = (const float*)d_in[22];
    const float* We2  = (const float*)d_in[23];
    const float* eemb2= (const float*)d_in[24];
    const float* al2  = (const float*)d_in[25];
    const float* ar2  = (const float*)d_in[26];
    const float* ae2  = (const float*)d_in[27];
    const float* resW2= (const float*)d_in[28];
    const int* src    = (const int*)d_in[29];
    const int* dst    = (const int*)d_in[30];
    const int* etype  = (const int*)d_in[31];

    const int n0 = in_sizes[0] / 128;
    const int n1 = in_sizes[1] / 256;
    const int n2 = in_sizes[2] / 64;
    const int N  = n0 + n1 + n2;
    const int E  = in_sizes[29];

    char* w = (char*)d_ws;
    auto alloc = [&](size_t bytes) {
        char* p = w;
        w += (bytes + 255) & ~(size_t)255;
        return p;
    };
    int*    counts  = (int*)alloc((size_t)N * 4);
    int*    offsets = (int*)alloc((size_t)(N + 1) * 4);
    int*    cursor  = (int*)alloc((size_t)N * 4);
    int*    partial = (int*)alloc(1024 * 4);
    int*    src_s   = (int*)alloc((size_t)E * 4);
    int*    et_s    = (int*)alloc((size_t)E * 4);
    ushort* h2res   = (ushort*)alloc((size_t)N * 256 * 2);
    ushort* a0b     = (ushort*)alloc((size_t)E * 8 * 2);
    ushort* h0bf    = (ushort*)alloc((size_t)N * 64 * 2);
    ushort* featb   = (ushort*)alloc((size_t)N * 256 * 2);
    ushort* h1bf    = (ushort*)alloc((size_t)N * 256 * 2);
    ushort* h2bf    = (ushort*)alloc((size_t)N * 256 * 2);
    float*  el      = (float*)alloc((size_t)N * 8 * 4);
    float*  er      = (float*)alloc((size_t)N * 8 * 4);
    float*  etatt   = (float*)alloc(6 * 8 * 4);
    ushort* Wt0     = (ushort*)alloc((size_t)256 * 64 * 2);
    ushort* Wt1     = (ushort*)alloc((size_t)256 * 256 * 2);
    ushort* WtR     = (ushort*)alloc((size_t)256 * 256 * 2);
    float*  feat2   = (float*)alloc((size_t)N * 16 * 4);
    float*  out     = (float*)d_out;

    const int TB = 256;
    int eb = (E + TB - 1) / TB;
    int nb1 = (N + 255) / 256;

    // ---- CSR build ----
    hipMemsetAsync(counts, 0, (size_t)N * 4, stream);
    hist_kernel<<<eb, TB, 0, stream>>>(dst, counts, E);
    scan_part<<<nb1, 256, 0, stream>>>(counts, offsets, partial, N);
    scan_top<<<1, 256, 0, stream>>>(partial, nb1);
    scan_add<<<nb1, 256, 0, stream>>>(offsets, partial, N);
    hipMemcpyAsync(cursor, offsets, (size_t)N * 4, hipMemcpyDeviceToDevice, stream);
    scatter_kernel<<<eb, TB, 0, stream>>>(src, dst, etype, cursor, src_s, et_s, E);

    // ---- weight prep ----
    wprep<<<(64 * 256 + TB - 1) / TB, TB, 0, stream>>>(W0, Wt0, 64, 256);
    wprep<<<(256 * 256 + TB - 1) / TB, TB, 0, stream>>>(W1, Wt1, 256, 256);
    wprep<<<(256 * 256 + TB - 1) / TB, TB, 0, stream>>>(resW1, WtR, 256, 256);

    // ---- input FC: h0bf = concat(x_i @ fcw_i + fcb_i) ----
    {
        dim3 g0(1, (n0 + 63) / 64);
        matmul64_fc<<<g0, TB, 0, stream>>>(x0, fcw0, fcb0, h0bf, n0, 128, 64);
        dim3 g1(1, (n1 + 63) / 64);
        matmul64_fc<<<g1, TB, 0, stream>>>(x1, fcw1, fcb1, h0bf + (long)n0 * 64, n1, 256, 64);
        dim3 g2(1, (n2 + 63) / 64);
        matmul64_fc<<<g2, TB, 0, stream>>>(x2, fcw2, fcb2, h0bf + (long)(n0 + n1) * 64, n2, 64, 64);
    }

    int nb_nh8 = (N * 8 + TB - 1) / TB;
    dim3 gg(256 / 128, (N + 127) / 128);

    // ---- layer 0 ----
    {
        gemm_bf16<<<gg, TB, 0, stream>>>(h0bf, Wt0, featb, N, 256, 64);
        attn_lr_b<8, 32><<<nb_nh8, TB, 0, stream>>>(featb, al0, ar0, el, er, N);
        etype_att<8><<<6, 512, 0, stream>>>(eemb0, We0, ae0, etatt);
        fused_edge_h8<false, true, false><<<N, 64, 0, stream>>>(
            offsets, src_s, et_s, el, er, etatt, featb, nullptr, a0b, nullptr, h1bf, N);
    }

    // ---- layer 1 ----
    {
        gemm_bf16<<<gg, TB, 0, stream>>>(h1bf, Wt1, featb, N, 256, 256);
        attn_lr_b<8, 32><<<nb_nh8, TB, 0, stream>>>(featb, al1, ar1, el, er, N);
        etype_att<8><<<6, 512, 0, stream>>>(eemb1, We1, ae1, etatt);
        gemm_bf16<<<gg, TB, 0, stream>>>(h1bf, WtR, h2res, N, 256, 256);
        fused_edge_h8<true, false, true><<<N, 64, 0, stream>>>(
            offsets, src_s, et_s, el, er, etatt, featb, a0b, nullptr, h2res, h2bf, N);
    }

    // ---- layer 2 (H=1, OUT=16, residual, no activation) ----
    {
        matmul_n16b<false><<<(N + 15) / 16, TB, 0, stream>>>(h2bf, W2, feat2, N, 256);
        int nb_nh1 = (N + TB - 1) / TB;
        attn_lr<1, 16><<<nb_nh1, TB, 0, stream>>>(feat2, al2, ar2, el, er, N);
        etype_att<1><<<6, 64, 0, stream>>>(eemb2, We2, ae2, etatt);
        fused_edge_h1<<<N, 64, 0, stream>>>(offsets, src_s, et_s, el, er, etatt, feat2, out, N);
        matmul_n16b<true><<<(N + 15) / 16, TB, 0, stream>>>(h2bf, resW2, out, N, 256);
    }
}